// Round 5
// baseline (3168.282 us; speedup 1.0000x reference)
//
#include <hip/hip_runtime.h>
#include <math.h>

#define NTOK 197
#define CD   768
#define NH   12
#define DH   64
#define NBATCH 64
#define RTOK 98
#define KTOK 99
#define THRN 1941   /* count(w >= thr) >= thr_idx+1 = 1941 */

__device__ __forceinline__ int clamp196(int v){ return ((unsigned)v > 196u) ? 196 : v; }

// ---------------- diagnostic fill ----------------
__global__ __launch_bounds__(256) void fill_kernel(float* __restrict__ out, int n, float val)
{
  int i = blockIdx.x*256 + threadIdx.x;
  if (i < n) out[i] = val;
}

// ---------------- LayerNorm (row length 768, one block per row) ----------------
__global__ __launch_bounds__(256) void ln_kernel(const float* __restrict__ xin,
                                                 const float* __restrict__ gam,
                                                 const float* __restrict__ bet,
                                                 float* __restrict__ outp)
{
  int row = blockIdx.x;
  int tid = threadIdx.x;
  long base = (long)row * CD;
  float v[3];
#pragma unroll
  for (int i=0;i<3;i++) v[i] = xin[base + tid + i*256];
  float s  = v[0]+v[1]+v[2];
  float s2 = v[0]*v[0]+v[1]*v[1]+v[2]*v[2];
#pragma unroll
  for (int off=32; off; off>>=1){ s += __shfl_down(s,off); s2 += __shfl_down(s2,off); }
  __shared__ float ps[4], ps2[4], mb[2];
  if ((tid&63)==0){ ps[tid>>6]=s; ps2[tid>>6]=s2; }
  __syncthreads();
  if (tid==0){
    float S  = ps[0]+ps[1]+ps[2]+ps[3];
    float S2 = ps2[0]+ps2[1]+ps2[2]+ps2[3];
    float m  = S / (float)CD;
    float var = S2 / (float)CD - m*m;
    mb[0]=m; mb[1]=1.0f/sqrtf(var + 1e-5f);
  }
  __syncthreads();
  float m=mb[0], inv=mb[1];
#pragma unroll
  for (int i=0;i<3;i++){
    int c = tid + i*256;
    outp[base+c] = (v[i]-m)*inv*gam[c] + bet[c];
  }
}

// ---------------- fp32 SGEMM, C = A@B (+epilogue), batched via z ----------------
// EPI 0: C f32 plain | 1: QKV scatter (q scaled, kT transposed, v) |
// EPI 3: +bias +resid -> f32 | 4: gelu(acc+bias) -> f32
struct GemmP {
  const float* A;        // [.., M, K]
  const float* B;        // [.., K, ldb]
  float*       C;
  int M, N, K, ldb, ldc;
  int zdiv;
  long as0, as1, bs0, bs1, cs0, cs1;
  const float* bias;
  const float* resid;
  float *q, *kT, *v;
};

template<int EPI>
__global__ __launch_bounds__(256) void gemm_k(GemmP p)
{
  __shared__ float As[16][64];   // [kk][m]
  __shared__ float Bs[16][64];   // [kk][n]
  int z = blockIdx.z;
  int zq = z / p.zdiv, zr = z - zq*p.zdiv;
  long aoff = zq*p.as0 + zr*p.as1;
  long boff = zq*p.bs0 + zr*p.bs1;
  long coff = zq*p.cs0 + zr*p.cs1;
  int m0 = blockIdx.y*64, n0 = blockIdx.x*64;
  int tid = threadIdx.x;
  int tx = tid & 15, ty = tid >> 4;
  int am = tid >> 2, ak = (tid & 3) * 4;   // A-stage: row am, k cols ak..ak+3
  int bk = tid >> 4, bn = (tid & 15) * 4;  // B-stage: k row bk, n cols bn..bn+3
  bool aVec = ((p.K & 3) == 0);
  float acc[4][4] = {};
  for (int k0 = 0; k0 < p.K; k0 += 16) {
    float aa[4] = {0.f,0.f,0.f,0.f};
    {
      int gm = m0 + am;
      if (gm < p.M) {
        const float* ap = p.A + aoff + (long)gm*p.K + k0 + ak;
        if (aVec) {
          float4 t = *(const float4*)ap;
          aa[0]=t.x; aa[1]=t.y; aa[2]=t.z; aa[3]=t.w;
        } else {
#pragma unroll
          for (int i=0;i<4;i++) if (k0+ak+i < p.K) aa[i] = ap[i];
        }
      }
    }
    float bb[4] = {0.f,0.f,0.f,0.f};
    {
      int gk = k0 + bk;
      if (gk < p.K) {
        const float* bp = p.B + boff + (long)gk*p.ldb + n0 + bn;
        if (n0 + bn + 3 < p.N) {
          float4 t = *(const float4*)bp;
          bb[0]=t.x; bb[1]=t.y; bb[2]=t.z; bb[3]=t.w;
        } else {
#pragma unroll
          for (int i=0;i<4;i++) if (n0+bn+i < p.N) bb[i] = bp[i];
        }
      }
    }
    __syncthreads();   // previous iteration's LDS reads complete
#pragma unroll
    for (int i=0;i<4;i++) As[ak+i][am] = aa[i];
#pragma unroll
    for (int i=0;i<4;i++) Bs[bk][bn+i] = bb[i];
    __syncthreads();
#pragma unroll
    for (int kk=0;kk<16;kk++){
      float4 av = *(const float4*)&As[kk][ty*4];
      float4 bv = *(const float4*)&Bs[kk][tx*4];
      float av4[4]={av.x,av.y,av.z,av.w};
      float bv4[4]={bv.x,bv.y,bv.z,bv.w};
#pragma unroll
      for (int i=0;i<4;i++)
#pragma unroll
        for (int j=0;j<4;j++) acc[i][j] = fmaf(av4[i], bv4[j], acc[i][j]);
    }
  }
#pragma unroll
  for (int i=0;i<4;i++){
    int gm = m0 + ty*4 + i;
    if (gm >= p.M) continue;
#pragma unroll
    for (int j=0;j<4;j++){
      int gn = n0 + tx*4 + j;
      if (gn >= p.N) continue;
      float val = acc[i][j];
      if (EPI == 0) {
        p.C[coff + (long)gm*p.ldc + gn] = val;
      } else if (EPI == 1) {   // QKV scatter (chunk-local batch = gm/197)
        int which = gn / CD;
        int rc = gn - which*CD;
        int hd = rc >> 6, dd = rc & 63;
        int cb = gm / NTOK, tok = gm - cb*NTOK;
        long bh = (long)cb*NH + hd;
        if (which == 0)      p.q [(bh*NTOK + tok)*DH + dd] = val * 0.125f;
        else if (which == 1) p.kT[(bh*DH + dd)*NTOK + tok] = val;
        else                 p.v [(bh*NTOK + tok)*DH + dd] = val;
      } else if (EPI == 3) {
        p.C[coff + (long)gm*p.ldc + gn] = val + p.bias[gn] + p.resid[(long)gm*p.N + gn];
      } else {   // EPI 4
        float u = val + p.bias[gn];
        p.C[coff + (long)gm*p.ldc + gn] = 0.5f*u*(1.0f + erff(u*0.70710678118654752f));
      }
    }
  }
}

// ---------------- softmax: one wave per row of 197, in-place fp32 ----------------
__global__ __launch_bounds__(256) void softmax_kernel(float* __restrict__ attn)
{
  long row = (long)blockIdx.x*4 + (threadIdx.x>>6);
  int ln = threadIdx.x & 63;
  float* rp = attn + row*NTOK;
  float v[4]; float mx = -3.4e38f;
#pragma unroll
  for (int i=0;i<4;i++){
    int c = ln + i*64;
    v[i] = (c < NTOK) ? rp[c] : -3.4e38f;
    mx = fmaxf(mx, v[i]);
  }
#pragma unroll
  for (int off=32; off; off>>=1) mx = fmaxf(mx, __shfl_xor(mx, off));
  float sum = 0.f;
#pragma unroll
  for (int i=0;i<4;i++){
    int c = ln + i*64;
    v[i] = (c < NTOK) ? expf(v[i]-mx) : 0.f;
    sum += v[i];
  }
#pragma unroll
  for (int off=32; off; off>>=1) sum += __shfl_xor(sum, off);
#pragma unroll
  for (int i=0;i<4;i++){
    int c = ln + i*64;
    if (c < NTOK) rp[c] = v[i] / sum;
  }
}

// ---------------- token selection (chunk-local attn, global idx; guarded writes) ----------------
__global__ __launch_bounds__(256) void select_kernel(const float* __restrict__ attn,
                                                     int* __restrict__ idx_kept,
                                                     int* __restrict__ idx_elim, int b0)
{
  int cb = blockIdx.x, tid = threadIdx.x;
  int b = b0 + cb;
  __shared__ float diag[NTOK-1];
  __shared__ int kept[NTOK];
  if (tid < NTOK-1) {
    int t = tid + 1;
    float s = 0.f;
#pragma unroll
    for (int h=0; h<NH; h++)
      s += attn[(((long)cb*NH + h)*NTOK + t)*NTOK + t];
    diag[tid] = s / 12.0f;
  }
  // pre-fill so degenerate data can never leave poison in the index arrays
  if (tid < KTOK) idx_kept[b*KTOK + tid] = 0;
  if (tid < RTOK) idx_elim[b*RTOK + tid] = 1;
  __syncthreads();
  if (tid < NTOK-1) {
    float dv = diag[tid];
    int r = 0;
    for (int m=0; m<NTOK-1; m++){
      float dm = diag[m];
      r += ((dm > dv) || (dm == dv && m < tid)) ? 1 : 0;
    }
    kept[tid+1] = (r < (NTOK-1-RTOK)) ? 1 : 0;   // top nk=98 ranks kept
  }
  __syncthreads();
  if (tid < NTOK-1) {
    int t = tid + 1;
    if (kept[t]) {
      int pos = 1;
      for (int s2=1; s2<t; s2++) pos += kept[s2];
      if (pos >= 1 && pos < KTOK) idx_kept[b*KTOK + pos] = t;
    } else {
      int pos = 0;
      for (int s2=1; s2<t; s2++) pos += 1 - kept[s2];
      if (pos >= 0 && pos < RTOK) idx_elim[b*RTOK + pos] = t;
    }
  }
  if (tid == 0) idx_kept[b*KTOK] = 0;
}

// ---------------- threshold = 1941-th largest of 9702 gathered weights ----------------
__global__ __launch_bounds__(256) void thr_kernel(const float* __restrict__ attn,
                                                  const int* __restrict__ idx_kept,
                                                  const int* __restrict__ idx_elim,
                                                  float* __restrict__ thr, int b0)
{
  int z = blockIdx.x;                 // chunk-local (cb*NH + h)
  int cb = z / NH;
  int b = b0 + cb;
  int tid = threadIdx.x;
  __shared__ float w[KTOK*RTOK];
  __shared__ int kidx[KTOK], eidx[RTOK];
  __shared__ int cw[4];
  __shared__ int ctot;
  if (tid < KTOK) kidx[tid] = clamp196(idx_kept[b*KTOK + tid]);
  if (tid < RTOK) eidx[tid] = clamp196(idx_elim[b*RTOK + tid]);
  __syncthreads();
  const float* ab = attn + (long)z*NTOK*NTOK;
  for (int i=tid; i<KTOK*RTOK; i+=256){
    int k = i / RTOK, e = i - k*RTOK;
    w[i] = ab[kidx[k]*NTOK + eidx[e]];
  }
  __syncthreads();
  unsigned lo = 0u, hi = 0x7f800000u;   // positive floats: bit pattern monotone
  while (hi - lo > 1u) {
    unsigned mid = (lo + hi) >> 1;
    float t = __uint_as_float(mid);
    int c = 0;
    for (int i=tid; i<KTOK*RTOK; i+=256) c += (w[i] >= t) ? 1 : 0;
#pragma unroll
    for (int off=32; off; off>>=1) c += __shfl_down(c, off);
    if ((tid & 63) == 0) cw[tid>>6] = c;
    __syncthreads();
    if (tid == 0) ctot = cw[0]+cw[1]+cw[2]+cw[3];
    __syncthreads();
    int tot = ctot;
    __syncthreads();
    if (tot >= THRN) lo = mid; else hi = mid;
  }
  if (tid == 0) thr[(long)b*NH + (z - cb*NH)] = __uint_as_float(lo);
}

// ---------------- propagation: x2(f32, into d_out) = x_kept + 0.1*(w' @ x_elim) ----------------
__global__ __launch_bounds__(256) void prop_kernel(const float* __restrict__ attn,
                                                   const float* __restrict__ x1c,
                                                   const int* __restrict__ idx_kept,
                                                   const int* __restrict__ idx_elim,
                                                   const float* __restrict__ thr,
                                                   float* __restrict__ x2, int b0)
{
  int z = blockIdx.x;                 // chunk-local (cb*NH + h)
  int cb = z / NH, h = z - cb*NH;
  int b = b0 + cb;
  int tid = threadIdx.x;
  __shared__ float xe[RTOK][DH];
  __shared__ int kidx[KTOK], eidx[RTOK];
  if (tid < KTOK) kidx[tid] = clamp196(idx_kept[b*KTOK + tid]);
  if (tid < RTOK) eidx[tid] = clamp196(idx_elim[b*RTOK + tid]);
  __syncthreads();
  for (int i=tid; i<RTOK*DH; i+=256){
    int e = i >> 6, d = i & 63;
    xe[e][d] = x1c[((long)cb*NTOK + eidx[e])*CD + h*DH + d];
  }
  __syncthreads();
  float tv = thr[(long)b*NH + h];
  int d = tid & 63;
  for (int k = tid>>6; k < KTOK; k += 4) {
    int kp = kidx[k];
    const float* arow = attn + ((long)z*NTOK + kp)*NTOK;
    float acc = 0.f;
    for (int e=0; e<RTOK; e++){
      float ww = arow[eidx[e]];
      if (ww >= tv) acc = fmaf(ww, xe[e][d], acc);
    }
    float xk = x1c[((long)cb*NTOK + kp)*CD + h*DH + d];
    x2[((long)b*KTOK + k)*CD + h*DH + d] = xk + 0.1f*acc;
  }
}

extern "C" void kernel_launch(void* const* d_in, const int* in_sizes, int n_in,
                              void* d_out, int out_size, void* d_ws, size_t ws_size,
                              hipStream_t stream)
{
  const float* x     = (const float*)d_in[0];
  const float* n1g   = (const float*)d_in[1];
  const float* n1b   = (const float*)d_in[2];
  const float* qkvw  = (const float*)d_in[3];
  const float* projw = (const float*)d_in[4];
  const float* projb = (const float*)d_in[5];
  const float* n2g   = (const float*)d_in[6];
  const float* n2b   = (const float*)d_in[7];
  const float* fc1w  = (const float*)d_in[8];
  const float* fc1b  = (const float*)d_in[9];
  const float* fc2w  = (const float*)d_in[10];
  const float* fc2b  = (const float*)d_in[11];
  float* out = (float*)d_out;

  const long XROW = (long)NTOK*CD;          // 151296
  const long AH   = (long)NTOK*NTOK;        // 38809
  const long AB   = (long)NH*AH;            // 465708
  const long QH   = (long)NH*NTOK*DH;       // 151296
  const long SMALL = 6336L + 6272L + 768L;  // idx_kept, idx_elim, thr
  const long PB   = AB + 4*XROW;            // 1,070,892 floats per batch
  const long MINREQ = SMALL + PB;           // ~4.34 MB

  long wsf = (long)(ws_size / 4);

  // ws too small: no-abort diagnostic — fill output with 1000*ws_MiB+1
  if (wsf < MINREQ) {
    float val = (float)(ws_size >> 20) * 1000.0f + 1.0f;
    fill_kernel<<<dim3((out_size+255)/256), 256, 0, stream>>>(out, out_size, val);
    return;
  }

  long avail = wsf - SMALL;
  int G = (int)(avail / PB);
  if (G > NBATCH) G = NBATCH;
  long rc = (avail / 3840L) / 64L * 64L;
  int RC = (int)(rc > 6336L ? 6336L : rc);

  float* ws = (float*)d_ws;
  int*   idx_kept = (int*)ws;
  int*   idx_elim = idx_kept + 6336;
  float* thr      = (float*)(idx_elim + 6272);
  float* base  = ws + SMALL;
  float* attnc = base;                         // G*AB
  float* h1c   = base + (long)G*AB;            // G*XROW (later aout)
  float* aoutc = h1c;
  float* qc    = h1c + (long)G*XROW;           // G*XROW (later x1)
  float* x1c   = qc;
  float* kTc   = qc + (long)G*XROW;            // G*XROW
  float* vc    = kTc + (long)G*XROW;           // G*XROW
  float* h2f   = base;                         // MLP phase reuses chunk area: RC*768
  float* gf    = base + (long)RC*CD;           // RC*3072

  for (int b0 = 0; b0 < NBATCH; b0 += G) {
    int GL = (NBATCH - b0 < G) ? (NBATCH - b0) : G;
    int MROW = GL*NTOK;
    // LN1 -> h1c
    ln_kernel<<<dim3(MROW), 256, 0, stream>>>(x + (long)b0*XROW, n1g, n1b, h1c);
    // QKV: h1c @ qkv_w -> qc(scaled), kTc(transposed), vc
    {
      GemmP p{}; p.A=h1c; p.B=qkvw;
      p.M=MROW; p.N=3*CD; p.K=CD; p.ldb=3*CD; p.ldc=0; p.zdiv=1;
      p.q=qc; p.kT=kTc; p.v=vc;
      gemm_k<1><<<dim3(36,(MROW+63)/64,1), 256, 0, stream>>>(p);
    }
    // S = q @ kT -> attnc
    {
      GemmP p{}; p.A=qc; p.B=kTc; p.C=attnc;
      p.M=NTOK; p.N=NTOK; p.K=DH; p.ldb=NTOK; p.ldc=NTOK; p.zdiv=1;
      p.as0=NTOK*DH; p.bs0=(long)DH*NTOK; p.cs0=AH;
      gemm_k<0><<<dim3(4,4,GL*NH), 256, 0, stream>>>(p);
    }
    // softmax in-place (NH*NTOK = 2364 rows/batch, divisible by 4)
    softmax_kernel<<<dim3(GL*591), 256, 0, stream>>>(attnc);
    // selection + threshold
    select_kernel<<<dim3(GL), 256, 0, stream>>>(attnc, idx_kept, idx_elim, b0);
    thr_kernel<<<dim3(GL*NH), 256, 0, stream>>>(attnc, idx_kept, idx_elim, thr, b0);
    // attn @ v -> aoutc [GL,197,768] (aliases h1c, dead after QKV)
    {
      GemmP p{}; p.A=attnc; p.B=vc; p.C=aoutc;
      p.M=NTOK; p.N=DH; p.K=NTOK; p.ldb=DH; p.ldc=CD; p.zdiv=NH;
      p.as0=AB; p.as1=AH; p.bs0=QH; p.bs1=(long)NTOK*DH; p.cs0=XROW; p.cs1=DH;
      gemm_k<0><<<dim3(1,4,GL*NH), 256, 0, stream>>>(p);
    }
    // proj: x1c = x[b0..] + aoutc @ proj_w + proj_b
    {
      GemmP p{}; p.A=aoutc; p.B=projw; p.C=x1c;
      p.M=MROW; p.N=CD; p.K=CD; p.ldb=CD; p.ldc=CD; p.zdiv=1;
      p.bias=projb; p.resid=x + (long)b0*XROW;
      gemm_k<3><<<dim3(12,(MROW+63)/64,1), 256, 0, stream>>>(p);
    }
    // propagation -> x2 (f32) stored in d_out
    prop_kernel<<<dim3(GL*NH), 256, 0, stream>>>(attnc, x1c, idx_kept, idx_elim, thr, out, b0);
  }

  // ---- MLP, row-chunked; x2 lives in d_out (f32), fc2 overwrites it in place ----
  for (int r0 = 0; r0 < NBATCH*KTOK; r0 += RC) {
    int RCL = (NBATCH*KTOK - r0 < RC) ? (NBATCH*KTOK - r0) : RC;
    // LN2: d_out rows -> h2f
    ln_kernel<<<dim3(RCL), 256, 0, stream>>>(out + (long)r0*CD, n2g, n2b, h2f);
    // fc1 + exact GELU -> gf [RCL,3072]
    {
      GemmP p{}; p.A=h2f; p.B=fc1w; p.C=gf;
      p.M=RCL; p.N=4*CD; p.K=CD; p.ldb=4*CD; p.ldc=4*CD; p.zdiv=1;
      p.bias=fc1b;
      gemm_k<4><<<dim3(48,(RCL+63)/64,1), 256, 0, stream>>>(p);
    }
    // fc2 + bias + x2 residual (in d_out) -> d_out
    {
      GemmP p{}; p.A=gf; p.B=fc2w; p.C=out + (long)r0*CD;
      p.M=RCL; p.N=CD; p.K=4*CD; p.ldb=CD; p.ldc=CD; p.zdiv=1;
      p.bias=fc2b; p.resid=out + (long)r0*CD;
      gemm_k<3><<<dim3(12,(RCL+63)/64,1), 256, 0, stream>>>(p);
    }
  }
}

// Round 6
// 2121.986 us; speedup vs baseline: 1.4931x; 1.4931x over previous
//
#include <hip/hip_runtime.h>
#include <math.h>

#define NTOK 197
#define CD   768
#define NH   12
#define DH   64
#define NBATCH 64
#define RTOK 98
#define KTOK 99
#define THRN 1941   /* count(w >= thr) >= thr_idx+1 = 1941 */

typedef __attribute__((ext_vector_type(8))) short short8;
typedef __attribute__((ext_vector_type(8))) unsigned short u16x8;
typedef __attribute__((ext_vector_type(4))) float floatx4;

__device__ __forceinline__ int clamp196(int v){ return ((unsigned)v > 196u) ? 196 : v; }
__device__ __forceinline__ unsigned short f2b(float f){
  unsigned u = __float_as_uint(f);
  return (unsigned short)((u + 0x7FFFu + ((u>>16)&1u)) >> 16);
}

// ---------------- diagnostic fill ----------------
__global__ __launch_bounds__(256) void fill_kernel(float* __restrict__ out, int n, float val)
{
  int i = blockIdx.x*256 + threadIdx.x;
  if (i < n) out[i] = val;
}

// ---------------- transpose+cast: dst[n][k] = bf16(src[k][col0+n]) ----------------
__global__ __launch_bounds__(256) void tcast_k(const float* __restrict__ src, int K, int ldn, int col0,
                                               unsigned short* __restrict__ dst)
{
  __shared__ float t[32][33];
  int n0 = blockIdx.x*32, k0 = blockIdx.y*32;
  int lx = threadIdx.x & 31, ly = threadIdx.x >> 5;
#pragma unroll
  for (int i=0;i<4;i++)
    t[ly + i*8][lx] = src[(long)(k0 + ly + i*8)*ldn + col0 + n0 + lx];
  __syncthreads();
#pragma unroll
  for (int i=0;i<4;i++){
    int n = ly + i*8;
    dst[(long)(n0 + n)*K + k0 + lx] = f2b(t[lx][n]);
  }
}

// ---------------- LayerNorm (row 768, one block per row; dual-dtype out) ----------------
__global__ __launch_bounds__(256) void ln_kernel(const float* __restrict__ xin,
                                                 const float* __restrict__ gam,
                                                 const float* __restrict__ bet,
                                                 float* __restrict__ outf,
                                                 unsigned short* __restrict__ outb)
{
  int row = blockIdx.x;
  int tid = threadIdx.x;
  long base = (long)row * CD;
  float v[3];
#pragma unroll
  for (int i=0;i<3;i++) v[i] = xin[base + tid + i*256];
  float s  = v[0]+v[1]+v[2];
  float s2 = v[0]*v[0]+v[1]*v[1]+v[2]*v[2];
#pragma unroll
  for (int off=32; off; off>>=1){ s += __shfl_down(s,off); s2 += __shfl_down(s2,off); }
  __shared__ float ps[4], ps2[4], mb[2];
  if ((tid&63)==0){ ps[tid>>6]=s; ps2[tid>>6]=s2; }
  __syncthreads();
  if (tid==0){
    float S  = ps[0]+ps[1]+ps[2]+ps[3];
    float S2 = ps2[0]+ps2[1]+ps2[2]+ps2[3];
    float m  = S / (float)CD;
    float var = S2 / (float)CD - m*m;
    mb[0]=m; mb[1]=1.0f/sqrtf(var + 1e-5f);
  }
  __syncthreads();
  float m=mb[0], inv=mb[1];
#pragma unroll
  for (int i=0;i<3;i++){
    int c = tid + i*256;
    float r = (v[i]-m)*inv*gam[c] + bet[c];
    if (outf) outf[base+c] = r;
    if (outb) outb[base+c] = f2b(r);
  }
}

// ---------------- fp32 SGEMM (selection path + attn@v), batched via z ----------------
// EPI 0: C f32 plain | 1: qk scatter (q scaled f32, kT f32; N=1536) | 2: C bf16 plain
struct GemmP {
  const float* A;        // [.., M, K]
  const float* B;        // [.., K, ldb]
  void*        C;
  int M, N, K, ldb, ldc;
  int zdiv;
  long as0, as1, bs0, bs1, cs0, cs1;
  float *q, *kT;
};

template<int EPI>
__global__ __launch_bounds__(256) void gemm_k(GemmP p)
{
  __shared__ float As[16][64];
  __shared__ float Bs[16][64];
  int z = blockIdx.z;
  int zq = z / p.zdiv, zr = z - zq*p.zdiv;
  long aoff = zq*p.as0 + zr*p.as1;
  long boff = zq*p.bs0 + zr*p.bs1;
  long coff = zq*p.cs0 + zr*p.cs1;
  int m0 = blockIdx.y*64, n0 = blockIdx.x*64;
  int tid = threadIdx.x;
  int tx = tid & 15, ty = tid >> 4;
  int am = tid >> 2, ak = (tid & 3) * 4;
  int bk = tid >> 4, bn = (tid & 15) * 4;
  bool aVec = ((p.K & 3) == 0);
  float acc[4][4] = {};
  for (int k0 = 0; k0 < p.K; k0 += 16) {
    float aa[4] = {0.f,0.f,0.f,0.f};
    {
      int gm = m0 + am;
      if (gm < p.M) {
        const float* ap = p.A + aoff + (long)gm*p.K + k0 + ak;
        if (aVec) {
          float4 t = *(const float4*)ap;
          aa[0]=t.x; aa[1]=t.y; aa[2]=t.z; aa[3]=t.w;
        } else {
#pragma unroll
          for (int i=0;i<4;i++) if (k0+ak+i < p.K) aa[i] = ap[i];
        }
      }
    }
    float bb[4] = {0.f,0.f,0.f,0.f};
    {
      int gk = k0 + bk;
      if (gk < p.K) {
        const float* bp = p.B + boff + (long)gk*p.ldb + n0 + bn;
        if (n0 + bn + 3 < p.N) {
          float4 t = *(const float4*)bp;
          bb[0]=t.x; bb[1]=t.y; bb[2]=t.z; bb[3]=t.w;
        } else {
#pragma unroll
          for (int i=0;i<4;i++) if (n0+bn+i < p.N) bb[i] = bp[i];
        }
      }
    }
    __syncthreads();
#pragma unroll
    for (int i=0;i<4;i++) As[ak+i][am] = aa[i];
#pragma unroll
    for (int i=0;i<4;i++) Bs[bk][bn+i] = bb[i];
    __syncthreads();
#pragma unroll
    for (int kk=0;kk<16;kk++){
      float4 av = *(const float4*)&As[kk][ty*4];
      float4 bv = *(const float4*)&Bs[kk][tx*4];
      float av4[4]={av.x,av.y,av.z,av.w};
      float bv4[4]={bv.x,bv.y,bv.z,bv.w};
#pragma unroll
      for (int i=0;i<4;i++)
#pragma unroll
        for (int j=0;j<4;j++) acc[i][j] = fmaf(av4[i], bv4[j], acc[i][j]);
    }
  }
#pragma unroll
  for (int i=0;i<4;i++){
    int gm = m0 + ty*4 + i;
    if (gm >= p.M) continue;
#pragma unroll
    for (int j=0;j<4;j++){
      int gn = n0 + tx*4 + j;
      if (gn >= p.N) continue;
      float val = acc[i][j];
      if (EPI == 0) {
        ((float*)p.C)[coff + (long)gm*p.ldc + gn] = val;
      } else if (EPI == 1) {   // qk scatter: N=1536, chunk-local batch = gm/197
        int which = (gn >= CD) ? 1 : 0;
        int rc = gn - which*CD;
        int hd = rc >> 6, dd = rc & 63;
        int cb = gm / NTOK, tok = gm - cb*NTOK;
        long bh = (long)cb*NH + hd;
        if (which == 0) p.q [(bh*NTOK + tok)*DH + dd] = val * 0.125f;
        else            p.kT[(bh*DH + dd)*NTOK + tok] = val;
      } else {                 // EPI 2: bf16 plain
        ((unsigned short*)p.C)[coff + (long)gm*p.ldc + gn] = f2b(val);
      }
    }
  }
}

// ---------------- bf16 MFMA GEMM: C[M,N] = A[M,K] @ Bt[N,K]^T ----------------
// EPI 0: f32 plain | 1: v-scatter f32 | 2: +bias+resid -> f32 | 3: gelu(+bias) -> bf16
struct MmP {
  const unsigned short* A;   // bf16 [M,K]
  const unsigned short* B;   // bf16 [N,K] (pre-transposed weights)
  void* C;
  const float* bias;
  const float* resid;        // row stride = ldc
  float* vout;
  int M, N, K, ldc;
};

template<int EPI>
__global__ __launch_bounds__(256) void mgemm_k(MmP p)
{
  __shared__ short As[128*32];
  __shared__ short Bs[128*32];
  int tid = threadIdx.x;
  int m0 = blockIdx.y*128, n0 = blockIdx.x*128;
  int w = tid>>6, l = tid&63;
  int wm = (w&1)*64, wn = (w>>1)*64;
  int lr = l&15, kq = (l>>4)*8;
  floatx4 acc[4][4];
#pragma unroll
  for (int i=0;i<4;i++)
#pragma unroll
    for (int j=0;j<4;j++) acc[i][j] = (floatx4){0.f,0.f,0.f,0.f};
  int r0i = tid>>2, q0 = (tid&3)*8;   // chunk tid: row r0i, k-offset q0 (8 shorts)
  int r1i = r0i + 64;                 // chunk tid+256
  for (int k0 = 0; k0 < p.K; k0 += 32) {
    u16x8 a0 = {0,0,0,0,0,0,0,0}, a1 = {0,0,0,0,0,0,0,0};
    { int gm = m0 + r0i;
      if (gm < p.M) a0 = *(const u16x8*)(p.A + (long)gm*p.K + k0 + q0); }
    { int gm = m0 + r1i;
      if (gm < p.M) a1 = *(const u16x8*)(p.A + (long)gm*p.K + k0 + q0); }
    u16x8 b0 = *(const u16x8*)(p.B + (long)(n0 + r0i)*p.K + k0 + q0);
    u16x8 b1 = *(const u16x8*)(p.B + (long)(n0 + r1i)*p.K + k0 + q0);
    __syncthreads();
    *(u16x8*)&As[r0i*32 + q0] = a0;
    *(u16x8*)&As[r1i*32 + q0] = a1;
    *(u16x8*)&Bs[r0i*32 + q0] = b0;
    *(u16x8*)&Bs[r1i*32 + q0] = b1;
    __syncthreads();
    short8 af[4], bfr[4];
#pragma unroll
    for (int mt=0;mt<4;mt++) af[mt]  = *(short8*)&As[(wm + mt*16 + lr)*32 + kq];
#pragma unroll
    for (int nt=0;nt<4;nt++) bfr[nt] = *(short8*)&Bs[(wn + nt*16 + lr)*32 + kq];
#pragma unroll
    for (int mt=0;mt<4;mt++)
#pragma unroll
      for (int nt=0;nt<4;nt++)
        acc[mt][nt] = __builtin_amdgcn_mfma_f32_16x16x32_bf16(af[mt], bfr[nt], acc[mt][nt], 0, 0, 0);
  }
  int rbase = (l>>4)*4;   // C/D: col=lane&15, row=(lane>>4)*4+reg  [m89-verified]
#pragma unroll
  for (int mt=0;mt<4;mt++){
#pragma unroll
    for (int r=0;r<4;r++){
      int gm = m0 + wm + mt*16 + rbase + r;
      if (gm >= p.M) continue;
#pragma unroll
      for (int nt=0;nt<4;nt++){
        int gn = n0 + wn + nt*16 + lr;
        float val = acc[mt][nt][r];
        if (EPI == 0) {
          ((float*)p.C)[(long)gm*p.ldc + gn] = val;
        } else if (EPI == 1) {   // v scatter
          int cb = gm / NTOK, tok = gm - cb*NTOK;
          int h = gn >> 6, d = gn & 63;
          p.vout[(((long)cb*NH + h)*NTOK + tok)*DH + d] = val;
        } else if (EPI == 2) {
          ((float*)p.C)[(long)gm*p.ldc + gn] = val + p.bias[gn] + p.resid[(long)gm*p.ldc + gn];
        } else {
          float u = val + p.bias[gn];
          ((unsigned short*)p.C)[(long)gm*p.ldc + gn] = f2b(0.5f*u*(1.0f + erff(u*0.70710678118654752f)));
        }
      }
    }
  }
}

// ---------------- softmax: one wave per row of 197, in-place fp32 ----------------
__global__ __launch_bounds__(256) void softmax_kernel(float* __restrict__ attn)
{
  long row = (long)blockIdx.x*4 + (threadIdx.x>>6);
  int ln = threadIdx.x & 63;
  float* rp = attn + row*NTOK;
  float v[4]; float mx = -3.4e38f;
#pragma unroll
  for (int i=0;i<4;i++){
    int c = ln + i*64;
    v[i] = (c < NTOK) ? rp[c] : -3.4e38f;
    mx = fmaxf(mx, v[i]);
  }
#pragma unroll
  for (int off=32; off; off>>=1) mx = fmaxf(mx, __shfl_xor(mx, off));
  float sum = 0.f;
#pragma unroll
  for (int i=0;i<4;i++){
    int c = ln + i*64;
    v[i] = (c < NTOK) ? expf(v[i]-mx) : 0.f;
    sum += v[i];
  }
#pragma unroll
  for (int off=32; off; off>>=1) sum += __shfl_xor(sum, off);
#pragma unroll
  for (int i=0;i<4;i++){
    int c = ln + i*64;
    if (c < NTOK) rp[c] = v[i] / sum;
  }
}

// ---------------- token selection (chunk-local attn, global idx; guarded) ----------------
__global__ __launch_bounds__(256) void select_kernel(const float* __restrict__ attn,
                                                     int* __restrict__ idx_kept,
                                                     int* __restrict__ idx_elim, int b0)
{
  int cb = blockIdx.x, tid = threadIdx.x;
  int b = b0 + cb;
  __shared__ float diag[NTOK-1];
  __shared__ int kept[NTOK];
  if (tid < NTOK-1) {
    int t = tid + 1;
    float s = 0.f;
#pragma unroll
    for (int h=0; h<NH; h++)
      s += attn[(((long)cb*NH + h)*NTOK + t)*NTOK + t];
    diag[tid] = s / 12.0f;
  }
  if (tid < KTOK) idx_kept[b*KTOK + tid] = 0;
  if (tid < RTOK) idx_elim[b*RTOK + tid] = 1;
  __syncthreads();
  if (tid < NTOK-1) {
    float dv = diag[tid];
    int r = 0;
    for (int m=0; m<NTOK-1; m++){
      float dm = diag[m];
      r += ((dm > dv) || (dm == dv && m < tid)) ? 1 : 0;
    }
    kept[tid+1] = (r < (NTOK-1-RTOK)) ? 1 : 0;
  }
  __syncthreads();
  if (tid < NTOK-1) {
    int t = tid + 1;
    if (kept[t]) {
      int pos = 1;
      for (int s2=1; s2<t; s2++) pos += kept[s2];
      if (pos >= 1 && pos < KTOK) idx_kept[b*KTOK + pos] = t;
    } else {
      int pos = 0;
      for (int s2=1; s2<t; s2++) pos += 1 - kept[s2];
      if (pos >= 0 && pos < RTOK) idx_elim[b*RTOK + pos] = t;
    }
  }
  if (tid == 0) idx_kept[b*KTOK] = 0;
}

// ---------------- threshold = 1941-th largest of 9702 gathered weights ----------------
__global__ __launch_bounds__(256) void thr_kernel(const float* __restrict__ attn,
                                                  const int* __restrict__ idx_kept,
                                                  const int* __restrict__ idx_elim,
                                                  float* __restrict__ thr, int b0)
{
  int z = blockIdx.x;
  int cb = z / NH;
  int b = b0 + cb;
  int tid = threadIdx.x;
  __shared__ float w[KTOK*RTOK];
  __shared__ int kidx[KTOK], eidx[RTOK];
  __shared__ int cw[4];
  __shared__ int ctot;
  if (tid < KTOK) kidx[tid] = clamp196(idx_kept[b*KTOK + tid]);
  if (tid < RTOK) eidx[tid] = clamp196(idx_elim[b*RTOK + tid]);
  __syncthreads();
  const float* ab = attn + (long)z*NTOK*NTOK;
  for (int i=tid; i<KTOK*RTOK; i+=256){
    int k = i / RTOK, e = i - k*RTOK;
    w[i] = ab[kidx[k]*NTOK + eidx[e]];
  }
  __syncthreads();
  unsigned lo = 0u, hi = 0x7f800000u;
  while (hi - lo > 1u) {
    unsigned mid = (lo + hi) >> 1;
    float t = __uint_as_float(mid);
    int c = 0;
    for (int i=tid; i<KTOK*RTOK; i+=256) c += (w[i] >= t) ? 1 : 0;
#pragma unroll
    for (int off=32; off; off>>=1) c += __shfl_down(c, off);
    if ((tid & 63) == 0) cw[tid>>6] = c;
    __syncthreads();
    if (tid == 0) ctot = cw[0]+cw[1]+cw[2]+cw[3];
    __syncthreads();
    int tot = ctot;
    __syncthreads();
    if (tot >= THRN) lo = mid; else hi = mid;
  }
  if (tid == 0) thr[(long)b*NH + (z - cb*NH)] = __uint_as_float(lo);
}

// ---------------- propagation: x2(f32, into d_out) = x_kept + 0.1*(w' @ x_elim) ----------------
__global__ __launch_bounds__(256) void prop_kernel(const float* __restrict__ attn,
                                                   const float* __restrict__ x1c,
                                                   const int* __restrict__ idx_kept,
                                                   const int* __restrict__ idx_elim,
                                                   const float* __restrict__ thr,
                                                   float* __restrict__ x2, int b0)
{
  int z = blockIdx.x;
  int cb = z / NH, h = z - cb*NH;
  int b = b0 + cb;
  int tid = threadIdx.x;
  __shared__ float xe[RTOK][DH];
  __shared__ int kidx[KTOK], eidx[RTOK];
  if (tid < KTOK) kidx[tid] = clamp196(idx_kept[b*KTOK + tid]);
  if (tid < RTOK) eidx[tid] = clamp196(idx_elim[b*RTOK + tid]);
  __syncthreads();
  for (int i=tid; i<RTOK*DH; i+=256){
    int e = i >> 6, d = i & 63;
    xe[e][d] = x1c[((long)cb*NTOK + eidx[e])*CD + h*DH + d];
  }
  __syncthreads();
  float tv = thr[(long)b*NH + h];
  int d = tid & 63;
  for (int k = tid>>6; k < KTOK; k += 4) {
    int kp = kidx[k];
    const float* arow = attn + ((long)z*NTOK + kp)*NTOK;
    float acc = 0.f;
    for (int e=0; e<RTOK; e++){
      float ww = arow[eidx[e]];
      if (ww >= tv) acc = fmaf(ww, xe[e][d], acc);
    }
    float xk = x1c[((long)cb*NTOK + kp)*CD + h*DH + d];
    x2[((long)b*KTOK + k)*CD + h*DH + d] = xk + 0.1f*acc;
  }
}

extern "C" void kernel_launch(void* const* d_in, const int* in_sizes, int n_in,
                              void* d_out, int out_size, void* d_ws, size_t ws_size,
                              hipStream_t stream)
{
  const float* x     = (const float*)d_in[0];
  const float* n1g   = (const float*)d_in[1];
  const float* n1b   = (const float*)d_in[2];
  const float* qkvw  = (const float*)d_in[3];
  const float* projw = (const float*)d_in[4];
  const float* projb = (const float*)d_in[5];
  const float* n2g   = (const float*)d_in[6];
  const float* n2b   = (const float*)d_in[7];
  const float* fc1w  = (const float*)d_in[8];
  const float* fc1b  = (const float*)d_in[9];
  const float* fc2w  = (const float*)d_in[10];
  const float* fc2b  = (const float*)d_in[11];
  float* out = (float*)d_out;

  const long XROW = (long)NTOK*CD;          // 151296
  const long AH   = (long)NTOK*NTOK;        // 38809
  const long AB   = (long)NH*AH;            // 465708
  const long QH   = (long)NH*NTOK*DH;       // 151296
  const long SMALL = 6336L + 6272L + 768L;  // 13376 floats
  const long WFIXF = 2949120L;              // bf16 weight transposes, in floats
  const long PB = AB + 4*XROW + XROW/2;     // 1,146,540 floats per batch
  const long MINREQ = SMALL + WFIXF + PB;   // ~16.4 MB

  long wsf = (long)(ws_size / 4);
  if (wsf < MINREQ) {
    float val = (float)(ws_size >> 20) * 1000.0f + 1.0f;
    fill_kernel<<<dim3((out_size+255)/256), 256, 0, stream>>>(out, out_size, val);
    return;
  }

  long avail = wsf - SMALL - WFIXF;
  int G = (int)(avail / PB);
  if (G > NBATCH) G = NBATCH;
  long rcl = (avail / 1920L) / 64L * 64L;
  int RC = (int)(rcl > 6336L ? 6336L : rcl);

  float* ws = (float*)d_ws;
  int*   idx_kept = (int*)ws;
  int*   idx_elim = idx_kept + 6336;
  float* thr      = (float*)(idx_elim + 6272);
  unsigned short* qkvwvT = (unsigned short*)(ws + SMALL);      // [768][768]
  unsigned short* projwT = qkvwvT + 589824;                    // [768][768]
  unsigned short* fc1wT  = projwT + 589824;                    // [3072][768]
  unsigned short* fc2wT  = fc1wT + 2359296;                    // [768][3072]
  float* base  = ws + SMALL + WFIXF;
  float* attnc = base;                          // G*AB f32
  float* h1f   = base + (long)G*AB;             // G*XROW f32
  float* qc    = h1f + (long)G*XROW;            // G*XROW f32 (x1c aliases)
  float* x1c   = qc;
  float* kTc   = qc + (long)G*XROW;             // G*XROW f32
  float* vc    = kTc + (long)G*XROW;            // G*XROW f32
  unsigned short* h1b = (unsigned short*)(vc + (long)G*XROW);  // G*XROW bf16 (aoutb aliases)
  unsigned short* aoutb = h1b;
  unsigned short* h2b = (unsigned short*)base;  // MLP reuse: RC*768 bf16
  unsigned short* gb  = h2b + (long)RC*CD;      // RC*3072 bf16

  // Phase 0: weight transpose+cast (once per call)
  tcast_k<<<dim3(24,24), 256, 0, stream>>>(qkvw, CD, 3*CD, 2*CD, qkvwvT);
  tcast_k<<<dim3(24,24), 256, 0, stream>>>(projw, CD, CD, 0, projwT);
  tcast_k<<<dim3(96,24), 256, 0, stream>>>(fc1w, CD, 4*CD, 0, fc1wT);
  tcast_k<<<dim3(24,96), 256, 0, stream>>>(fc2w, 4*CD, CD, 0, fc2wT);

  for (int b0 = 0; b0 < NBATCH; b0 += G) {
    int GL = (NBATCH - b0 < G) ? (NBATCH - b0) : G;
    int MROW = GL*NTOK;
    // LN1 -> h1f fp32 (selection path) + h1b bf16 (value path)
    ln_kernel<<<dim3(MROW), 256, 0, stream>>>(x + (long)b0*XROW, n1g, n1b, h1f, h1b);
    // qk fp32 gemm: h1f @ qkvw[:, :1536] -> qc(scaled), kTc(transposed)
    {
      GemmP p{}; p.A=h1f; p.B=qkvw;
      p.M=MROW; p.N=2*CD; p.K=CD; p.ldb=3*CD; p.ldc=0; p.zdiv=1;
      p.q=qc; p.kT=kTc;
      gemm_k<1><<<dim3(24,(MROW+63)/64,1), 256, 0, stream>>>(p);
    }
    // v bf16 MFMA gemm: h1b @ qkvwvT^T -> vc fp32 scatter
    {
      MmP p{}; p.A=h1b; p.B=qkvwvT; p.vout=vc;
      p.M=MROW; p.N=CD; p.K=CD; p.ldc=CD;
      mgemm_k<1><<<dim3(6,(MROW+127)/128,1), 256, 0, stream>>>(p);
    }
    // S = q @ kT -> attnc fp32
    {
      GemmP p{}; p.A=qc; p.B=kTc; p.C=attnc;
      p.M=NTOK; p.N=NTOK; p.K=DH; p.ldb=NTOK; p.ldc=NTOK; p.zdiv=1;
      p.as0=NTOK*DH; p.bs0=(long)DH*NTOK; p.cs0=AH;
      gemm_k<0><<<dim3(4,4,GL*NH), 256, 0, stream>>>(p);
    }
    softmax_kernel<<<dim3(GL*591), 256, 0, stream>>>(attnc);
    select_kernel<<<dim3(GL), 256, 0, stream>>>(attnc, idx_kept, idx_elim, b0);
    thr_kernel<<<dim3(GL*NH), 256, 0, stream>>>(attnc, idx_kept, idx_elim, thr, b0);
    // attn @ v -> aoutb bf16 [GL*197, 768]
    {
      GemmP p{}; p.A=attnc; p.B=vc; p.C=aoutb;
      p.M=NTOK; p.N=DH; p.K=NTOK; p.ldb=DH; p.ldc=CD; p.zdiv=NH;
      p.as0=AB; p.as1=AH; p.bs0=QH; p.bs1=(long)NTOK*DH; p.cs0=XROW; p.cs1=DH;
      gemm_k<2><<<dim3(1,4,GL*NH), 256, 0, stream>>>(p);
    }
    // proj MFMA: x1c = x + aoutb @ projwT^T + proj_b (fp32 out)
    {
      MmP p{}; p.A=aoutb; p.B=projwT; p.C=x1c;
      p.M=MROW; p.N=CD; p.K=CD; p.ldc=CD;
      p.bias=projb; p.resid=x + (long)b0*XROW;
      mgemm_k<2><<<dim3(6,(MROW+127)/128,1), 256, 0, stream>>>(p);
    }
    prop_kernel<<<dim3(GL*NH), 256, 0, stream>>>(attnc, x1c, idx_kept, idx_elim, thr, out, b0);
  }

  // ---- MLP, row-chunked; x2 lives in d_out (f32), fc2 overwrites in place ----
  for (int r0 = 0; r0 < NBATCH*KTOK; r0 += RC) {
    int RCL = (NBATCH*KTOK - r0 < RC) ? (NBATCH*KTOK - r0) : RC;
    ln_kernel<<<dim3(RCL), 256, 0, stream>>>(out + (long)r0*CD, n2g, n2b, nullptr, h2b);
    // fc1 MFMA + gelu -> gb bf16
    {
      MmP p{}; p.A=h2b; p.B=fc1wT; p.C=gb;
      p.M=RCL; p.N=4*CD; p.K=CD; p.ldc=4*CD; p.bias=fc1b;
      mgemm_k<3><<<dim3(24,(RCL+127)/128,1), 256, 0, stream>>>(p);
    }
    // fc2 MFMA + bias + resid -> d_out fp32
    {
      MmP p{}; p.A=gb; p.B=fc2wT; p.C=out + (long)r0*CD;
      p.M=RCL; p.N=CD; p.K=4*CD; p.ldc=CD;
      p.bias=fc2b; p.resid=out + (long)r0*CD;
      mgemm_k<2><<<dim3(6,(RCL+127)/128,1), 256, 0, stream>>>(p);
    }
  }
}

// Round 7
// 1183.727 us; speedup vs baseline: 2.6765x; 1.7926x over previous
//
#include <hip/hip_runtime.h>
#include <math.h>

#define NTOK 197
#define CD   768
#define NH   12
#define DH   64
#define NBATCH 64
#define RTOK 98
#define KTOK 99
#define THRN 1941   /* count(w >= thr) >= thr_idx+1 = 1941 */

typedef __attribute__((ext_vector_type(8))) short short8;
typedef __attribute__((ext_vector_type(8))) unsigned short u16x8;
typedef __attribute__((ext_vector_type(4))) float floatx4;

__device__ __forceinline__ int clamp196(int v){ return ((unsigned)v > 196u) ? 196 : v; }
__device__ __forceinline__ unsigned short f2b(float f){
  unsigned u = __float_as_uint(f);
  return (unsigned short)((u + 0x7FFFu + ((u>>16)&1u)) >> 16);
}
__device__ __forceinline__ float us2f(unsigned short u){ return __uint_as_float(((unsigned)u)<<16); }

// ---------------- diagnostic fill ----------------
__global__ __launch_bounds__(256) void fill_kernel(float* __restrict__ out, int n, float val)
{
  int i = blockIdx.x*256 + threadIdx.x;
  if (i < n) out[i] = val;
}

// ---------------- transpose+cast: dst[n][k] = bf16(src[k][col0+n]) ----------------
__global__ __launch_bounds__(256) void tcast_k(const float* __restrict__ src, int K, int ldn, int col0,
                                               unsigned short* __restrict__ dst)
{
  __shared__ float t[32][33];
  int n0 = blockIdx.x*32, k0 = blockIdx.y*32;
  int lx = threadIdx.x & 31, ly = threadIdx.x >> 5;
#pragma unroll
  for (int i=0;i<4;i++)
    t[ly + i*8][lx] = src[(long)(k0 + ly + i*8)*ldn + col0 + n0 + lx];
  __syncthreads();
#pragma unroll
  for (int i=0;i<4;i++){
    int n = ly + i*8;
    dst[(long)(n0 + n)*K + k0 + lx] = f2b(t[lx][n]);
  }
}

// ---------------- LayerNorm (row 768, one block per row; dual-dtype out) ----------------
__global__ __launch_bounds__(256) void ln_kernel(const float* __restrict__ xin,
                                                 const float* __restrict__ gam,
                                                 const float* __restrict__ bet,
                                                 float* __restrict__ outf,
                                                 unsigned short* __restrict__ outb)
{
  int row = blockIdx.x;
  int tid = threadIdx.x;
  long base = (long)row * CD;
  float v[3];
#pragma unroll
  for (int i=0;i<3;i++) v[i] = xin[base + tid + i*256];
  float s  = v[0]+v[1]+v[2];
  float s2 = v[0]*v[0]+v[1]*v[1]+v[2]*v[2];
#pragma unroll
  for (int off=32; off; off>>=1){ s += __shfl_down(s,off); s2 += __shfl_down(s2,off); }
  __shared__ float ps[4], ps2[4], mb[2];
  if ((tid&63)==0){ ps[tid>>6]=s; ps2[tid>>6]=s2; }
  __syncthreads();
  if (tid==0){
    float S  = ps[0]+ps[1]+ps[2]+ps[3];
    float S2 = ps2[0]+ps2[1]+ps2[2]+ps2[3];
    float m  = S / (float)CD;
    float var = S2 / (float)CD - m*m;
    mb[0]=m; mb[1]=1.0f/sqrtf(var + 1e-5f);
  }
  __syncthreads();
  float m=mb[0], inv=mb[1];
#pragma unroll
  for (int i=0;i<3;i++){
    int c = tid + i*256;
    float r = (v[i]-m)*inv*gam[c] + bet[c];
    if (outf) outf[base+c] = r;
    if (outb) outb[base+c] = f2b(r);
  }
}

// ---------------- fp32 SGEMM (selection path + attn@v), batched via z ----------------
// EPI 0: C f32 plain | 1: qk scatter (q scaled f32, kT f32; N=1536) | 2: C bf16 plain
// BF16B: B matrix is bf16 (u16)
struct GemmP {
  const float* A;        // [.., M, K]
  const void*  B;        // [.., K, ldb] f32 or bf16
  void*        C;
  int M, N, K, ldb, ldc;
  int zdiv;
  long as0, as1, bs0, bs1, cs0, cs1;
  float *q, *kT;
};

template<int EPI, int BF16B>
__global__ __launch_bounds__(256) void gemm_k(GemmP p)
{
  __shared__ float As[16][64];
  __shared__ float Bs[16][64];
  int z = blockIdx.z;
  int zq = z / p.zdiv, zr = z - zq*p.zdiv;
  long aoff = zq*p.as0 + zr*p.as1;
  long boff = zq*p.bs0 + zr*p.bs1;
  long coff = zq*p.cs0 + zr*p.cs1;
  int m0 = blockIdx.y*64, n0 = blockIdx.x*64;
  int tid = threadIdx.x;
  int tx = tid & 15, ty = tid >> 4;
  int am = tid >> 2, ak = (tid & 3) * 4;
  int bk = tid >> 4, bn = (tid & 15) * 4;
  bool aVec = ((p.K & 3) == 0);
  float acc[4][4] = {};
  for (int k0 = 0; k0 < p.K; k0 += 16) {
    float aa[4] = {0.f,0.f,0.f,0.f};
    {
      int gm = m0 + am;
      if (gm < p.M) {
        const float* ap = p.A + aoff + (long)gm*p.K + k0 + ak;
        if (aVec) {
          float4 t = *(const float4*)ap;
          aa[0]=t.x; aa[1]=t.y; aa[2]=t.z; aa[3]=t.w;
        } else {
#pragma unroll
          for (int i=0;i<4;i++) if (k0+ak+i < p.K) aa[i] = ap[i];
        }
      }
    }
    float bb[4] = {0.f,0.f,0.f,0.f};
    {
      int gk = k0 + bk;
      if (gk < p.K) {
        long idx = boff + (long)gk*p.ldb + n0 + bn;
        if (BF16B) {
          const unsigned short* bp = (const unsigned short*)p.B + idx;
          if (n0 + bn + 3 < p.N) {
            ushort4 t = *(const ushort4*)bp;
            bb[0]=us2f(t.x); bb[1]=us2f(t.y); bb[2]=us2f(t.z); bb[3]=us2f(t.w);
          } else {
#pragma unroll
            for (int i=0;i<4;i++) if (n0+bn+i < p.N) bb[i] = us2f(bp[i]);
          }
        } else {
          const float* bp = (const float*)p.B + idx;
          if (n0 + bn + 3 < p.N) {
            float4 t = *(const float4*)bp;
            bb[0]=t.x; bb[1]=t.y; bb[2]=t.z; bb[3]=t.w;
          } else {
#pragma unroll
            for (int i=0;i<4;i++) if (n0+bn+i < p.N) bb[i] = bp[i];
          }
        }
      }
    }
    __syncthreads();
#pragma unroll
    for (int i=0;i<4;i++) As[ak+i][am] = aa[i];
#pragma unroll
    for (int i=0;i<4;i++) Bs[bk][bn+i] = bb[i];
    __syncthreads();
#pragma unroll
    for (int kk=0;kk<16;kk++){
      float4 av = *(const float4*)&As[kk][ty*4];
      float4 bv = *(const float4*)&Bs[kk][tx*4];
      float av4[4]={av.x,av.y,av.z,av.w};
      float bv4[4]={bv.x,bv.y,bv.z,bv.w};
#pragma unroll
      for (int i=0;i<4;i++)
#pragma unroll
        for (int j=0;j<4;j++) acc[i][j] = fmaf(av4[i], bv4[j], acc[i][j]);
    }
  }
#pragma unroll
  for (int i=0;i<4;i++){
    int gm = m0 + ty*4 + i;
    if (gm >= p.M) continue;
#pragma unroll
    for (int j=0;j<4;j++){
      int gn = n0 + tx*4 + j;
      if (gn >= p.N) continue;
      float val = acc[i][j];
      if (EPI == 0) {
        ((float*)p.C)[coff + (long)gm*p.ldc + gn] = val;
      } else if (EPI == 1) {   // qk scatter: N=1536, chunk-local batch = gm/197
        int which = (gn >= CD) ? 1 : 0;
        int rc = gn - which*CD;
        int hd = rc >> 6, dd = rc & 63;
        int cb = gm / NTOK, tok = gm - cb*NTOK;
        long bh = (long)cb*NH + hd;
        if (which == 0) p.q [(bh*NTOK + tok)*DH + dd] = val * 0.125f;
        else            p.kT[(bh*DH + dd)*NTOK + tok] = val;
      } else {                 // EPI 2: bf16 plain
        ((unsigned short*)p.C)[coff + (long)gm*p.ldc + gn] = f2b(val);
      }
    }
  }
}

// ---------------- bf16 MFMA GEMM: C[M,N] = A[M,K] @ Bt[N,K]^T ----------------
// AF32: A is fp32, converted to bf16 during staging.
// EPI 1: v-scatter bf16 | 2: +bias+resid -> f32 | 3: gelu(+bias) -> bf16
struct MmP {
  const unsigned short* A;   // bf16 [M,K] (AF32=0)
  const float* Af;           // f32  [M,K] (AF32=1)
  const unsigned short* B;   // bf16 [N,K] (pre-transposed weights)
  void* C;
  const float* bias;
  const float* resid;        // row stride = ldc
  unsigned short* vout;
  int M, N, K, ldc;
};

template<int AF32, int EPI>
__global__ __launch_bounds__(256) void mgemm_k(MmP p)
{
  __shared__ short As[128*32];
  __shared__ short Bs[128*32];
  int tid = threadIdx.x;
  int m0 = blockIdx.y*128, n0 = blockIdx.x*128;
  int w = tid>>6, l = tid&63;
  int wm = (w&1)*64, wn = (w>>1)*64;
  int lr = l&15, kq = (l>>4)*8;
  floatx4 acc[4][4];
#pragma unroll
  for (int i=0;i<4;i++)
#pragma unroll
    for (int j=0;j<4;j++) acc[i][j] = (floatx4){0.f,0.f,0.f,0.f};
  int r0i = tid>>2, q0 = (tid&3)*8;
  int r1i = r0i + 64;
  for (int k0 = 0; k0 < p.K; k0 += 32) {
    u16x8 a0 = {0,0,0,0,0,0,0,0}, a1 = {0,0,0,0,0,0,0,0};
    if (AF32) {
      { int gm = m0 + r0i;
        if (gm < p.M) {
          const float* ap = p.Af + (long)gm*p.K + k0 + q0;
          float4 t0 = *(const float4*)ap, t1 = *(const float4*)(ap+4);
          a0[0]=f2b(t0.x); a0[1]=f2b(t0.y); a0[2]=f2b(t0.z); a0[3]=f2b(t0.w);
          a0[4]=f2b(t1.x); a0[5]=f2b(t1.y); a0[6]=f2b(t1.z); a0[7]=f2b(t1.w);
        } }
      { int gm = m0 + r1i;
        if (gm < p.M) {
          const float* ap = p.Af + (long)gm*p.K + k0 + q0;
          float4 t0 = *(const float4*)ap, t1 = *(const float4*)(ap+4);
          a1[0]=f2b(t0.x); a1[1]=f2b(t0.y); a1[2]=f2b(t0.z); a1[3]=f2b(t0.w);
          a1[4]=f2b(t1.x); a1[5]=f2b(t1.y); a1[6]=f2b(t1.z); a1[7]=f2b(t1.w);
        } }
    } else {
      { int gm = m0 + r0i;
        if (gm < p.M) a0 = *(const u16x8*)(p.A + (long)gm*p.K + k0 + q0); }
      { int gm = m0 + r1i;
        if (gm < p.M) a1 = *(const u16x8*)(p.A + (long)gm*p.K + k0 + q0); }
    }
    u16x8 b0 = *(const u16x8*)(p.B + (long)(n0 + r0i)*p.K + k0 + q0);
    u16x8 b1 = *(const u16x8*)(p.B + (long)(n0 + r1i)*p.K + k0 + q0);
    __syncthreads();
    *(u16x8*)&As[r0i*32 + q0] = a0;
    *(u16x8*)&As[r1i*32 + q0] = a1;
    *(u16x8*)&Bs[r0i*32 + q0] = b0;
    *(u16x8*)&Bs[r1i*32 + q0] = b1;
    __syncthreads();
    short8 af[4], bfr[4];
#pragma unroll
    for (int mt=0;mt<4;mt++) af[mt]  = *(short8*)&As[(wm + mt*16 + lr)*32 + kq];
#pragma unroll
    for (int nt=0;nt<4;nt++) bfr[nt] = *(short8*)&Bs[(wn + nt*16 + lr)*32 + kq];
#pragma unroll
    for (int mt=0;mt<4;mt++)
#pragma unroll
      for (int nt=0;nt<4;nt++)
        acc[mt][nt] = __builtin_amdgcn_mfma_f32_16x16x32_bf16(af[mt], bfr[nt], acc[mt][nt], 0, 0, 0);
  }
  int rbase = (l>>4)*4;   // C/D: col=lane&15, row=(lane>>4)*4+reg  [m89-verified]
#pragma unroll
  for (int mt=0;mt<4;mt++){
#pragma unroll
    for (int r=0;r<4;r++){
      int gm = m0 + wm + mt*16 + rbase + r;
      if (gm >= p.M) continue;
#pragma unroll
      for (int nt=0;nt<4;nt++){
        int gn = n0 + wn + nt*16 + lr;
        float val = acc[mt][nt][r];
        if (EPI == 1) {   // v scatter -> bf16 [bh][tok][dh]
          int cb = gm / NTOK, tok = gm - cb*NTOK;
          int h = gn >> 6, d = gn & 63;
          p.vout[(((long)cb*NH + h)*NTOK + tok)*DH + d] = f2b(val);
        } else if (EPI == 2) {
          ((float*)p.C)[(long)gm*p.ldc + gn] = val + p.bias[gn] + p.resid[(long)gm*p.ldc + gn];
        } else {
          float u = val + p.bias[gn];
          ((unsigned short*)p.C)[(long)gm*p.ldc + gn] = f2b(0.5f*u*(1.0f + erff(u*0.70710678118654752f)));
        }
      }
    }
  }
}

// ---------------- softmax: one wave per row of 197, in-place fp32 ----------------
__global__ __launch_bounds__(256) void softmax_kernel(float* __restrict__ attn)
{
  long row = (long)blockIdx.x*4 + (threadIdx.x>>6);
  int ln = threadIdx.x & 63;
  float* rp = attn + row*NTOK;
  float v[4]; float mx = -3.4e38f;
#pragma unroll
  for (int i=0;i<4;i++){
    int c = ln + i*64;
    v[i] = (c < NTOK) ? rp[c] : -3.4e38f;
    mx = fmaxf(mx, v[i]);
  }
#pragma unroll
  for (int off=32; off; off>>=1) mx = fmaxf(mx, __shfl_xor(mx, off));
  float sum = 0.f;
#pragma unroll
  for (int i=0;i<4;i++){
    int c = ln + i*64;
    v[i] = (c < NTOK) ? expf(v[i]-mx) : 0.f;
    sum += v[i];
  }
#pragma unroll
  for (int off=32; off; off>>=1) sum += __shfl_xor(sum, off);
#pragma unroll
  for (int i=0;i<4;i++){
    int c = ln + i*64;
    if (c < NTOK) rp[c] = v[i] / sum;
  }
}

// ---------------- token selection (chunk-local attn, global idx; guarded) ----------------
__global__ __launch_bounds__(256) void select_kernel(const float* __restrict__ attn,
                                                     int* __restrict__ idx_kept,
                                                     int* __restrict__ idx_elim, int b0)
{
  int cb = blockIdx.x, tid = threadIdx.x;
  int b = b0 + cb;
  __shared__ float diag[NTOK-1];
  __shared__ int kept[NTOK];
  if (tid < NTOK-1) {
    int t = tid + 1;
    float s = 0.f;
#pragma unroll
    for (int h=0; h<NH; h++)
      s += attn[(((long)cb*NH + h)*NTOK + t)*NTOK + t];
    diag[tid] = s / 12.0f;
  }
  if (tid < KTOK) idx_kept[b*KTOK + tid] = 0;
  if (tid < RTOK) idx_elim[b*RTOK + tid] = 1;
  __syncthreads();
  if (tid < NTOK-1) {
    float dv = diag[tid];
    int r = 0;
    for (int m=0; m<NTOK-1; m++){
      float dm = diag[m];
      r += ((dm > dv) || (dm == dv && m < tid)) ? 1 : 0;
    }
    kept[tid+1] = (r < (NTOK-1-RTOK)) ? 1 : 0;
  }
  __syncthreads();
  if (tid < NTOK-1) {
    int t = tid + 1;
    if (kept[t]) {
      int pos = 1;
      for (int s2=1; s2<t; s2++) pos += kept[s2];
      if (pos >= 1 && pos < KTOK) idx_kept[b*KTOK + pos] = t;
    } else {
      int pos = 0;
      for (int s2=1; s2<t; s2++) pos += 1 - kept[s2];
      if (pos >= 0 && pos < RTOK) idx_elim[b*RTOK + pos] = t;
    }
  }
  if (tid == 0) idx_kept[b*KTOK] = 0;
}

// ---------------- fused threshold + propagation ----------------
// Per (b,h): gather w[99][98] -> LDS, exact order-stat threshold by bitwise
// binary search, zero sub-threshold in LDS, dense FMA from LDS.
// x2(f32, into d_out) = x_kept + 0.1*(w' @ x_elim)
__global__ __launch_bounds__(256) void prop_kernel(const float* __restrict__ attn,
                                                   const float* __restrict__ x1c,
                                                   const int* __restrict__ idx_kept,
                                                   const int* __restrict__ idx_elim,
                                                   float* __restrict__ x2, int b0)
{
  int z = blockIdx.x;                 // chunk-local (cb*NH + h)
  int cb = z / NH, h = z - cb*NH;
  int b = b0 + cb;
  int tid = threadIdx.x;
  __shared__ float w[KTOK*RTOK];          // 38808 B, fp32 (exact threshold)
  __shared__ unsigned short xe[RTOK*DH];  // 12544 B, bf16 (value path)
  __shared__ int kidx[KTOK], eidx[RTOK];
  __shared__ int cw[4];
  __shared__ int ctot;
  if (tid < KTOK) kidx[tid] = clamp196(idx_kept[b*KTOK + tid]);
  if (tid < RTOK) eidx[tid] = clamp196(idx_elim[b*RTOK + tid]);
  __syncthreads();
  const float* ab = attn + (long)z*NTOK*NTOK;
  for (int i=tid; i<KTOK*RTOK; i+=256){
    int k = i / RTOK, e = i - k*RTOK;
    w[i] = ab[kidx[k]*NTOK + eidx[e]];
  }
  for (int i=tid; i<RTOK*DH; i+=256){
    int e = i >> 6, d = i & 63;
    xe[i] = f2b(x1c[((long)cb*NTOK + eidx[e])*CD + h*DH + d]);
  }
  __syncthreads();
  // exact 1941-th largest via bitwise binary search on positive-float patterns
  unsigned lo = 0u, hi = 0x3f800001u;   // softmax weights in [0,1]
  while (hi - lo > 1u) {
    unsigned mid = (lo + hi) >> 1;
    float t = __uint_as_float(mid);
    int c = 0;
    for (int i=tid; i<KTOK*RTOK; i+=256) c += (w[i] >= t) ? 1 : 0;
#pragma unroll
    for (int off=32; off; off>>=1) c += __shfl_down(c, off);
    if ((tid & 63) == 0) cw[tid>>6] = c;
    __syncthreads();
    if (tid == 0) ctot = cw[0]+cw[1]+cw[2]+cw[3];
    __syncthreads();
    int tot = ctot;
    __syncthreads();
    if (tot >= THRN) lo = mid; else hi = mid;
  }
  float tv = __uint_as_float(lo);
  // zero sub-threshold weights in LDS (removes compare from inner loop)
  for (int i=tid; i<KTOK*RTOK; i+=256) if (w[i] < tv) w[i] = 0.f;
  __syncthreads();
  int d = tid & 63;
  for (int k = tid>>6; k < KTOK; k += 4) {
    const float* wr = &w[k*RTOK];
    float acc = 0.f;
#pragma unroll 7
    for (int e=0; e<RTOK; e++)
      acc = fmaf(wr[e], us2f(xe[(e<<6) + d]), acc);
    float xk = x1c[((long)cb*NTOK + kidx[k])*CD + h*DH + d];
    x2[((long)b*KTOK + k)*CD + h*DH + d] = xk + 0.1f*acc;
  }
}

extern "C" void kernel_launch(void* const* d_in, const int* in_sizes, int n_in,
                              void* d_out, int out_size, void* d_ws, size_t ws_size,
                              hipStream_t stream)
{
  const float* x     = (const float*)d_in[0];
  const float* n1g   = (const float*)d_in[1];
  const float* n1b   = (const float*)d_in[2];
  const float* qkvw  = (const float*)d_in[3];
  const float* projw = (const float*)d_in[4];
  const float* projb = (const float*)d_in[5];
  const float* n2g   = (const float*)d_in[6];
  const float* n2b   = (const float*)d_in[7];
  const float* fc1w  = (const float*)d_in[8];
  const float* fc1b  = (const float*)d_in[9];
  const float* fc2w  = (const float*)d_in[10];
  const float* fc2b  = (const float*)d_in[11];
  float* out = (float*)d_out;

  const long XROW = (long)NTOK*CD;          // 151296
  const long AH   = (long)NTOK*NTOK;        // 38809
  const long AB   = (long)NH*AH;            // 465708
  const long QH   = (long)NH*NTOK*DH;       // 151296
  const long SMALL = 6336L + 6272L;         // 12608 floats (idx_kept, idx_elim)
  const long WFIXF = 2949120L;              // bf16 weight transposes, in floats
  const long PB = AB + 3*XROW + XROW/2;     // 995,244 floats per batch
  const long MINREQ = SMALL + WFIXF + PB;   // ~15.8 MB

  long wsf = (long)(ws_size / 4);
  if (wsf < MINREQ) {
    float val = (float)(ws_size >> 20) * 1000.0f + 1.0f;
    fill_kernel<<<dim3((out_size+255)/256), 256, 0, stream>>>(out, out_size, val);
    return;
  }

  long avail = wsf - SMALL - WFIXF;
  int G = (int)(avail / PB);
  if (G > NBATCH) G = NBATCH;
  long rcl = (avail / 1920L) / 64L * 64L;
  int RC = (int)(rcl > 6336L ? 6336L : rcl);

  float* ws = (float*)d_ws;
  int*   idx_kept = (int*)ws;
  int*   idx_elim = idx_kept + 6336;
  unsigned short* qkvwvT = (unsigned short*)(ws + SMALL);      // [768][768]
  unsigned short* projwT = qkvwvT + 589824;                    // [768][768]
  unsigned short* fc1wT  = projwT + 589824;                    // [3072][768]
  unsigned short* fc2wT  = fc1wT + 2359296;                    // [768][3072]
  float* base  = ws + SMALL + WFIXF;
  float* attnc = base;                          // G*AB f32
  float* h1f   = base + (long)G*AB;             // G*XROW f32 (aoutb bf16 aliases)
  unsigned short* aoutb = (unsigned short*)h1f;
  float* qc    = h1f + (long)G*XROW;            // G*XROW f32 (x1c aliases)
  float* x1c   = qc;
  float* kTc   = qc + (long)G*XROW;             // G*XROW f32
  unsigned short* vc = (unsigned short*)(kTc + (long)G*XROW);  // G*XROW bf16
  unsigned short* h2b = (unsigned short*)base;  // MLP reuse: RC*768 bf16
  unsigned short* gb  = h2b + (long)RC*CD;      // RC*3072 bf16

  // Phase 0: weight transpose+cast (once per call)
  tcast_k<<<dim3(24,24), 256, 0, stream>>>(qkvw, CD, 3*CD, 2*CD, qkvwvT);
  tcast_k<<<dim3(24,24), 256, 0, stream>>>(projw, CD, CD, 0, projwT);
  tcast_k<<<dim3(96,24), 256, 0, stream>>>(fc1w, CD, 4*CD, 0, fc1wT);
  tcast_k<<<dim3(24,96), 256, 0, stream>>>(fc2w, 4*CD, CD, 0, fc2wT);

  for (int b0 = 0; b0 < NBATCH; b0 += G) {
    int GL = (NBATCH - b0 < G) ? (NBATCH - b0) : G;
    int MROW = GL*NTOK;
    // LN1 -> h1f fp32 only
    ln_kernel<<<dim3(MROW), 256, 0, stream>>>(x + (long)b0*XROW, n1g, n1b, h1f, nullptr);
    // qk fp32 gemm: h1f @ qkvw[:, :1536] -> qc(scaled), kTc(transposed)
    {
      GemmP p{}; p.A=h1f; p.B=qkvw;
      p.M=MROW; p.N=2*CD; p.K=CD; p.ldb=3*CD; p.ldc=0; p.zdiv=1;
      p.q=qc; p.kT=kTc;
      gemm_k<1,0><<<dim3(24,(MROW+63)/64,1), 256, 0, stream>>>(p);
    }
    // v MFMA gemm (A fp32 converted in-kernel): h1f @ qkvwvT^T -> vc bf16 scatter
    {
      MmP p{}; p.Af=h1f; p.B=qkvwvT; p.vout=vc;
      p.M=MROW; p.N=CD; p.K=CD; p.ldc=CD;
      mgemm_k<1,1><<<dim3(6,(MROW+127)/128,1), 256, 0, stream>>>(p);
    }
    // S = q @ kT -> attnc fp32
    {
      GemmP p{}; p.A=qc; p.B=kTc; p.C=attnc;
      p.M=NTOK; p.N=NTOK; p.K=DH; p.ldb=NTOK; p.ldc=NTOK; p.zdiv=1;
      p.as0=NTOK*DH; p.bs0=(long)DH*NTOK; p.cs0=AH;
      gemm_k<0,0><<<dim3(4,4,GL*NH), 256, 0, stream>>>(p);
    }
    softmax_kernel<<<dim3(GL*591), 256, 0, stream>>>(attnc);
    select_kernel<<<dim3(GL), 256, 0, stream>>>(attnc, idx_kept, idx_elim, b0);
    // attn @ v (bf16 B) -> aoutb bf16 [GL*197, 768]
    {
      GemmP p{}; p.A=attnc; p.B=vc; p.C=aoutb;
      p.M=NTOK; p.N=DH; p.K=NTOK; p.ldb=DH; p.ldc=CD; p.zdiv=NH;
      p.as0=AB; p.as1=AH; p.bs0=QH; p.bs1=(long)NTOK*DH; p.cs0=XROW; p.cs1=DH;
      gemm_k<2,1><<<dim3(1,4,GL*NH), 256, 0, stream>>>(p);
    }
    // proj MFMA: x1c = x + aoutb @ projwT^T + proj_b (fp32 out)
    {
      MmP p{}; p.A=aoutb; p.B=projwT; p.C=x1c;
      p.M=MROW; p.N=CD; p.K=CD; p.ldc=CD;
      p.bias=projb; p.resid=x + (long)b0*XROW;
      mgemm_k<0,2><<<dim3(6,(MROW+127)/128,1), 256, 0, stream>>>(p);
    }
    // fused threshold + propagation -> x2 (f32) in d_out
    prop_kernel<<<dim3(GL*NH), 256, 0, stream>>>(attnc, x1c, idx_kept, idx_elim, out, b0);
  }

  // ---- MLP, row-chunked; x2 lives in d_out (f32), fc2 overwrites in place ----
  for (int r0 = 0; r0 < NBATCH*KTOK; r0 += RC) {
    int RCL = (NBATCH*KTOK - r0 < RC) ? (NBATCH*KTOK - r0) : RC;
    ln_kernel<<<dim3(RCL), 256, 0, stream>>>(out + (long)r0*CD, n2g, n2b, nullptr, h2b);
    // fc1 MFMA + gelu -> gb bf16
    {
      MmP p{}; p.A=h2b; p.B=fc1wT; p.C=gb;
      p.M=RCL; p.N=4*CD; p.K=CD; p.ldc=4*CD; p.bias=fc1b;
      mgemm_k<0,3><<<dim3(24,(RCL+127)/128,1), 256, 0, stream>>>(p);
    }
    // fc2 MFMA + bias + resid -> d_out fp32
    {
      MmP p{}; p.A=gb; p.B=fc2wT; p.C=out + (long)r0*CD;
      p.M=RCL; p.N=CD; p.K=4*CD; p.ldc=CD;
      p.bias=fc2b; p.resid=out + (long)r0*CD;
      mgemm_k<0,2><<<dim3(6,(RCL+127)/128,1), 256, 0, stream>>>(p);
    }
  }
}

// Round 9
// 854.299 us; speedup vs baseline: 3.7086x; 1.3856x over previous
//
#include <hip/hip_runtime.h>
#include <math.h>

#define NTOK 197
#define CD   768
#define NH   12
#define DH   64
#define NBATCH 64
#define RTOK 98
#define KTOK 99
#define THRN 1941   /* count(w >= thr) >= thr_idx+1 = 1941 */

typedef __attribute__((ext_vector_type(8))) short short8;
typedef __attribute__((ext_vector_type(8))) unsigned short u16x8;
typedef __attribute__((ext_vector_type(4))) float floatx4;

__device__ __forceinline__ int clamp196(int v){ return ((unsigned)v > 196u) ? 196 : v; }
__device__ __forceinline__ unsigned short f2b(float f){
  unsigned u = __float_as_uint(f);
  return (unsigned short)((u + 0x7FFFu + ((u>>16)&1u)) >> 16);
}
__device__ __forceinline__ float us2f(unsigned short u){ return __uint_as_float(((unsigned)u)<<16); }

// load up to 8 fp32 (rem valid), split into bf16 hi + bf16 lo
__device__ __forceinline__ void ldsplit(const float* ap, int rem, u16x8& h, u16x8& l){
  float v[8];
  if (rem >= 8) {
    float4 t0 = *(const float4*)ap, t1 = *(const float4*)(ap+4);
    v[0]=t0.x; v[1]=t0.y; v[2]=t0.z; v[3]=t0.w;
    v[4]=t1.x; v[5]=t1.y; v[6]=t1.z; v[7]=t1.w;
  } else {
#pragma unroll
    for (int j=0;j<8;j++) v[j] = (j < rem) ? ap[j] : 0.f;
  }
#pragma unroll
  for (int j=0;j<8;j++){
    unsigned short hh = f2b(v[j]);
    h[j] = hh;
    l[j] = f2b(v[j] - us2f(hh));
  }
}

// ---------------- diagnostic fill ----------------
__global__ __launch_bounds__(256) void fill_kernel(float* __restrict__ out, int n, float val)
{
  int i = blockIdx.x*256 + threadIdx.x;
  if (i < n) out[i] = val;
}

// ---------------- transpose+cast: dst[n][k] = bf16(src[k][col0+n]) ----------------
__global__ __launch_bounds__(256) void tcast_k(const float* __restrict__ src, int K, int ldn, int col0,
                                               unsigned short* __restrict__ dst)
{
  __shared__ float t[32][33];
  int n0 = blockIdx.x*32, k0 = blockIdx.y*32;
  int lx = threadIdx.x & 31, ly = threadIdx.x >> 5;
#pragma unroll
  for (int i=0;i<4;i++)
    t[ly + i*8][lx] = src[(long)(k0 + ly + i*8)*ldn + col0 + n0 + lx];
  __syncthreads();
#pragma unroll
  for (int i=0;i<4;i++){
    int n = ly + i*8;
    dst[(long)(n0 + n)*K + k0 + lx] = f2b(t[lx][n]);
  }
}

// ---------------- transpose + hi/lo split: dsth/dstl[n][k] from src[k][col0+n] ----------------
__global__ __launch_bounds__(256) void tcast3_k(const float* __restrict__ src, int K, int ldn, int col0,
                                                unsigned short* __restrict__ dsth,
                                                unsigned short* __restrict__ dstl)
{
  __shared__ float t[32][33];
  int n0 = blockIdx.x*32, k0 = blockIdx.y*32;
  int lx = threadIdx.x & 31, ly = threadIdx.x >> 5;
#pragma unroll
  for (int i=0;i<4;i++)
    t[ly + i*8][lx] = src[(long)(k0 + ly + i*8)*ldn + col0 + n0 + lx];
  __syncthreads();
#pragma unroll
  for (int i=0;i<4;i++){
    int n = ly + i*8;
    float v = t[lx][n];
    unsigned short h = f2b(v);
    dsth[(long)(n0 + n)*K + k0 + lx] = h;
    dstl[(long)(n0 + n)*K + k0 + lx] = f2b(v - us2f(h));
  }
}

// ---------------- LayerNorm (row 768, one block per row; dual-dtype out) ----------------
__global__ __launch_bounds__(256) void ln_kernel(const float* __restrict__ xin,
                                                 const float* __restrict__ gam,
                                                 const float* __restrict__ bet,
                                                 float* __restrict__ outf,
                                                 unsigned short* __restrict__ outb)
{
  int row = blockIdx.x;
  int tid = threadIdx.x;
  long base = (long)row * CD;
  float v[3];
#pragma unroll
  for (int i=0;i<3;i++) v[i] = xin[base + tid + i*256];
  float s  = v[0]+v[1]+v[2];
  float s2 = v[0]*v[0]+v[1]*v[1]+v[2]*v[2];
#pragma unroll
  for (int off=32; off; off>>=1){ s += __shfl_down(s,off); s2 += __shfl_down(s2,off); }
  __shared__ float ps[4], ps2[4], mb[2];
  if ((tid&63)==0){ ps[tid>>6]=s; ps2[tid>>6]=s2; }
  __syncthreads();
  if (tid==0){
    float S  = ps[0]+ps[1]+ps[2]+ps[3];
    float S2 = ps2[0]+ps2[1]+ps2[2]+ps2[3];
    float m  = S / (float)CD;
    float var = S2 / (float)CD - m*m;
    mb[0]=m; mb[1]=1.0f/sqrtf(var + 1e-5f);
  }
  __syncthreads();
  float m=mb[0], inv=mb[1];
#pragma unroll
  for (int i=0;i<3;i++){
    int c = tid + i*256;
    float r = (v[i]-m)*inv*gam[c] + bet[c];
    if (outf) outf[base+c] = r;
    if (outb) outb[base+c] = f2b(r);
  }
}

// ---------------- fp32 SGEMM (attn@v only now), batched via z ----------------
// EPI 2: C bf16 plain; BF16B: B matrix is bf16
struct GemmP {
  const float* A;
  const void*  B;
  void*        C;
  int M, N, K, ldb, ldc;
  int zdiv;
  long as0, as1, bs0, bs1, cs0, cs1;
};

template<int EPI, int BF16B>
__global__ __launch_bounds__(256) void gemm_k(GemmP p)
{
  __shared__ float As[16][64];
  __shared__ float Bs[16][64];
  int z = blockIdx.z;
  int zq = z / p.zdiv, zr = z - zq*p.zdiv;
  long aoff = zq*p.as0 + zr*p.as1;
  long boff = zq*p.bs0 + zr*p.bs1;
  long coff = zq*p.cs0 + zr*p.cs1;
  int m0 = blockIdx.y*64, n0 = blockIdx.x*64;
  int tid = threadIdx.x;
  int tx = tid & 15, ty = tid >> 4;
  int am = tid >> 2, ak = (tid & 3) * 4;
  int bk = tid >> 4, bn = (tid & 15) * 4;
  bool aVec = ((p.K & 3) == 0);
  float acc[4][4] = {};
  for (int k0 = 0; k0 < p.K; k0 += 16) {
    float aa[4] = {0.f,0.f,0.f,0.f};
    {
      int gm = m0 + am;
      if (gm < p.M) {
        const float* ap = p.A + aoff + (long)gm*p.K + k0 + ak;
        if (aVec) {
          float4 t = *(const float4*)ap;
          aa[0]=t.x; aa[1]=t.y; aa[2]=t.z; aa[3]=t.w;
        } else {
#pragma unroll
          for (int i=0;i<4;i++) if (k0+ak+i < p.K) aa[i] = ap[i];
        }
      }
    }
    float bb[4] = {0.f,0.f,0.f,0.f};
    {
      int gk = k0 + bk;
      if (gk < p.K) {
        long idx = boff + (long)gk*p.ldb + n0 + bn;
        if (BF16B) {
          const unsigned short* bp = (const unsigned short*)p.B + idx;
          if (n0 + bn + 3 < p.N) {
            ushort4 t = *(const ushort4*)bp;
            bb[0]=us2f(t.x); bb[1]=us2f(t.y); bb[2]=us2f(t.z); bb[3]=us2f(t.w);
          } else {
#pragma unroll
            for (int i=0;i<4;i++) if (n0+bn+i < p.N) bb[i] = us2f(bp[i]);
          }
        } else {
          const float* bp = (const float*)p.B + idx;
          if (n0 + bn + 3 < p.N) {
            float4 t = *(const float4*)bp;
            bb[0]=t.x; bb[1]=t.y; bb[2]=t.z; bb[3]=t.w;
          } else {
#pragma unroll
            for (int i=0;i<4;i++) if (n0+bn+i < p.N) bb[i] = bp[i];
          }
        }
      }
    }
    __syncthreads();
#pragma unroll
    for (int i=0;i<4;i++) As[ak+i][am] = aa[i];
#pragma unroll
    for (int i=0;i<4;i++) Bs[bk][bn+i] = bb[i];
    __syncthreads();
#pragma unroll
    for (int kk=0;kk<16;kk++){
      float4 av = *(const float4*)&As[kk][ty*4];
      float4 bv = *(const float4*)&Bs[kk][tx*4];
      float av4[4]={av.x,av.y,av.z,av.w};
      float bv4[4]={bv.x,bv.y,bv.z,bv.w};
#pragma unroll
      for (int i=0;i<4;i++)
#pragma unroll
        for (int j=0;j<4;j++) acc[i][j] = fmaf(av4[i], bv4[j], acc[i][j]);
    }
  }
#pragma unroll
  for (int i=0;i<4;i++){
    int gm = m0 + ty*4 + i;
    if (gm >= p.M) continue;
#pragma unroll
    for (int j=0;j<4;j++){
      int gn = n0 + tx*4 + j;
      if (gn >= p.N) continue;
      float val = acc[i][j];
      if (EPI == 2) {
        ((unsigned short*)p.C)[coff + (long)gm*p.ldc + gn] = f2b(val);
      } else {
        ((float*)p.C)[coff + (long)gm*p.ldc + gn] = val;
      }
    }
  }
}

// ---------------- bf16 MFMA GEMM: C[M,N] = A[M,K] @ Bt[N,K]^T (single precision) ----------------
// AF32: A fp32 converted in staging. EPI 1: v-scatter bf16 | 2: +bias+resid -> f32 | 3: gelu(+bias) -> bf16
struct MmP {
  const unsigned short* A;
  const float* Af;
  const unsigned short* B;
  void* C;
  const float* bias;
  const float* resid;
  unsigned short* vout;
  int M, N, K, ldc;
};

template<int AF32, int EPI>
__global__ __launch_bounds__(256) void mgemm_k(MmP p)
{
  __shared__ short As[128*32];
  __shared__ short Bs[128*32];
  int tid = threadIdx.x;
  int m0 = blockIdx.y*128, n0 = blockIdx.x*128;
  int w = tid>>6, l = tid&63;
  int wm = (w&1)*64, wn = (w>>1)*64;
  int lr = l&15, kq = (l>>4)*8;
  floatx4 acc[4][4];
#pragma unroll
  for (int i=0;i<4;i++)
#pragma unroll
    for (int j=0;j<4;j++) acc[i][j] = (floatx4){0.f,0.f,0.f,0.f};
  int r0i = tid>>2, q0 = (tid&3)*8;
  int r1i = r0i + 64;
  for (int k0 = 0; k0 < p.K; k0 += 32) {
    u16x8 a0 = {0,0,0,0,0,0,0,0}, a1 = {0,0,0,0,0,0,0,0};
    if (AF32) {
      { int gm = m0 + r0i;
        if (gm < p.M) {
          const float* ap = p.Af + (long)gm*p.K + k0 + q0;
          float4 t0 = *(const float4*)ap, t1 = *(const float4*)(ap+4);
          a0[0]=f2b(t0.x); a0[1]=f2b(t0.y); a0[2]=f2b(t0.z); a0[3]=f2b(t0.w);
          a0[4]=f2b(t1.x); a0[5]=f2b(t1.y); a0[6]=f2b(t1.z); a0[7]=f2b(t1.w);
        } }
      { int gm = m0 + r1i;
        if (gm < p.M) {
          const float* ap = p.Af + (long)gm*p.K + k0 + q0;
          float4 t0 = *(const float4*)ap, t1 = *(const float4*)(ap+4);
          a1[0]=f2b(t0.x); a1[1]=f2b(t0.y); a1[2]=f2b(t0.z); a1[3]=f2b(t0.w);
          a1[4]=f2b(t1.x); a1[5]=f2b(t1.y); a1[6]=f2b(t1.z); a1[7]=f2b(t1.w);
        } }
    } else {
      { int gm = m0 + r0i;
        if (gm < p.M) a0 = *(const u16x8*)(p.A + (long)gm*p.K + k0 + q0); }
      { int gm = m0 + r1i;
        if (gm < p.M) a1 = *(const u16x8*)(p.A + (long)gm*p.K + k0 + q0); }
    }
    u16x8 b0 = *(const u16x8*)(p.B + (long)(n0 + r0i)*p.K + k0 + q0);
    u16x8 b1 = *(const u16x8*)(p.B + (long)(n0 + r1i)*p.K + k0 + q0);
    __syncthreads();
    *(u16x8*)&As[r0i*32 + q0] = a0;
    *(u16x8*)&As[r1i*32 + q0] = a1;
    *(u16x8*)&Bs[r0i*32 + q0] = b0;
    *(u16x8*)&Bs[r1i*32 + q0] = b1;
    __syncthreads();
    short8 af[4], bfr[4];
#pragma unroll
    for (int mt=0;mt<4;mt++) af[mt]  = *(short8*)&As[(wm + mt*16 + lr)*32 + kq];
#pragma unroll
    for (int nt=0;nt<4;nt++) bfr[nt] = *(short8*)&Bs[(wn + nt*16 + lr)*32 + kq];
#pragma unroll
    for (int mt=0;mt<4;mt++)
#pragma unroll
      for (int nt=0;nt<4;nt++)
        acc[mt][nt] = __builtin_amdgcn_mfma_f32_16x16x32_bf16(af[mt], bfr[nt], acc[mt][nt], 0, 0, 0);
  }
  int rbase = (l>>4)*4;   // C/D: col=lane&15, row=(lane>>4)*4+reg  [m89-verified]
#pragma unroll
  for (int mt=0;mt<4;mt++){
#pragma unroll
    for (int r=0;r<4;r++){
      int gm = m0 + wm + mt*16 + rbase + r;
      if (gm >= p.M) continue;
#pragma unroll
      for (int nt=0;nt<4;nt++){
        int gn = n0 + wn + nt*16 + lr;
        float val = acc[mt][nt][r];
        if (EPI == 1) {   // v scatter -> bf16 [bh][tok][dh]
          int cb = gm / NTOK, tok = gm - cb*NTOK;
          int h = gn >> 6, d = gn & 63;
          p.vout[(((long)cb*NH + h)*NTOK + tok)*DH + d] = f2b(val);
        } else if (EPI == 2) {
          ((float*)p.C)[(long)gm*p.ldc + gn] = val + p.bias[gn] + p.resid[(long)gm*p.ldc + gn];
        } else {
          float u = val + p.bias[gn];
          ((unsigned short*)p.C)[(long)gm*p.ldc + gn] = f2b(0.5f*u*(1.0f + erff(u*0.70710678118654752f)));
        }
      }
    }
  }
}

// ---------------- bf16x3 MFMA GEMM (fp32-accuracy): C = A @ B^T ----------------
// A fp32 [z][M][K]; B: BPRE=1 pre-split bf16 hi/lo [N][K]; BPRE=0 fp32 [z][N][K].
// acc += Ah*Bh + Ah*Bl + Al*Bh  (error ~2^-17 relative)
// EPI 0: C f32 [z][M][ldc] | 1: qk scatter (gn<768: q*0.125, else k; both [bh][tok][dh] f32)
struct Mm3P {
  const float* A;
  const float* Bf;
  const unsigned short* Bh;
  const unsigned short* Bl;
  float* C;
  float *q, *k;
  long az, bz, cz;
  int M, N, K, ldc;
};

template<int BPRE, int EPI>
__global__ __launch_bounds__(256) void mgemm3_k(Mm3P p)
{
  __shared__ short Ah[128*32], Al[128*32], Bh[128*32], Bl[128*32];
  int tid = threadIdx.x;
  int z = blockIdx.z;
  const float* Az = p.A + (long)z*p.az;
  int m0 = blockIdx.y*128, n0 = blockIdx.x*128;
  int w = tid>>6, l = tid&63;
  int wm = (w&1)*64, wn = (w>>1)*64;
  int lr = l&15, kq = (l>>4)*8;
  floatx4 acc[4][4];
#pragma unroll
  for (int i=0;i<4;i++)
#pragma unroll
    for (int j=0;j<4;j++) acc[i][j] = (floatx4){0.f,0.f,0.f,0.f};
  int r0i = tid>>2, q0 = (tid&3)*8;
  int r1i = r0i + 64;
  for (int k0 = 0; k0 < p.K; k0 += 32) {
    u16x8 ah0={0,0,0,0,0,0,0,0}, al0={0,0,0,0,0,0,0,0};
    u16x8 ah1={0,0,0,0,0,0,0,0}, al1={0,0,0,0,0,0,0,0};
    u16x8 bh0={0,0,0,0,0,0,0,0}, bl0={0,0,0,0,0,0,0,0};
    u16x8 bh1={0,0,0,0,0,0,0,0}, bl1={0,0,0,0,0,0,0,0};
    { int gm = m0 + r0i;
      if (gm < p.M) ldsplit(Az + (long)gm*p.K + k0 + q0, p.K - k0 - q0, ah0, al0); }
    { int gm = m0 + r1i;
      if (gm < p.M) ldsplit(Az + (long)gm*p.K + k0 + q0, p.K - k0 - q0, ah1, al1); }
    if (BPRE) {
      { int gn = n0 + r0i;
        if (gn < p.N) {
          bh0 = *(const u16x8*)(p.Bh + (long)gn*p.K + k0 + q0);
          bl0 = *(const u16x8*)(p.Bl + (long)gn*p.K + k0 + q0);
        } }
      { int gn = n0 + r1i;
        if (gn < p.N) {
          bh1 = *(const u16x8*)(p.Bh + (long)gn*p.K + k0 + q0);
          bl1 = *(const u16x8*)(p.Bl + (long)gn*p.K + k0 + q0);
        } }
    } else {
      const float* Bz = p.Bf + (long)z*p.bz;
      { int gn = n0 + r0i;
        if (gn < p.N) ldsplit(Bz + (long)gn*p.K + k0 + q0, p.K - k0 - q0, bh0, bl0); }
      { int gn = n0 + r1i;
        if (gn < p.N) ldsplit(Bz + (long)gn*p.K + k0 + q0, p.K - k0 - q0, bh1, bl1); }
    }
    __syncthreads();
    *(u16x8*)&Ah[r0i*32 + q0] = ah0;
    *(u16x8*)&Ah[r1i*32 + q0] = ah1;
    *(u16x8*)&Al[r0i*32 + q0] = al0;
    *(u16x8*)&Al[r1i*32 + q0] = al1;
    *(u16x8*)&Bh[r0i*32 + q0] = bh0;
    *(u16x8*)&Bh[r1i*32 + q0] = bh1;
    *(u16x8*)&Bl[r0i*32 + q0] = bl0;
    *(u16x8*)&Bl[r1i*32 + q0] = bl1;
    __syncthreads();
    short8 afh[4], afl[4], bfh[4], bfl[4];
#pragma unroll
    for (int mt=0;mt<4;mt++){
      afh[mt] = *(short8*)&Ah[(wm + mt*16 + lr)*32 + kq];
      afl[mt] = *(short8*)&Al[(wm + mt*16 + lr)*32 + kq];
    }
#pragma unroll
    for (int nt=0;nt<4;nt++){
      bfh[nt] = *(short8*)&Bh[(wn + nt*16 + lr)*32 + kq];
      bfl[nt] = *(short8*)&Bl[(wn + nt*16 + lr)*32 + kq];
    }
#pragma unroll
    for (int mt=0;mt<4;mt++)
#pragma unroll
      for (int nt=0;nt<4;nt++){
        acc[mt][nt] = __builtin_amdgcn_mfma_f32_16x16x32_bf16(afh[mt], bfh[nt], acc[mt][nt], 0, 0, 0);
        acc[mt][nt] = __builtin_amdgcn_mfma_f32_16x16x32_bf16(afh[mt], bfl[nt], acc[mt][nt], 0, 0, 0);
        acc[mt][nt] = __builtin_amdgcn_mfma_f32_16x16x32_bf16(afl[mt], bfh[nt], acc[mt][nt], 0, 0, 0);
      }
  }
  int rbase = (l>>4)*4;
#pragma unroll
  for (int mt=0;mt<4;mt++){
#pragma unroll
    for (int r=0;r<4;r++){
      int gm = m0 + wm + mt*16 + rbase + r;
      if (gm >= p.M) continue;
#pragma unroll
      for (int nt=0;nt<4;nt++){
        int gn = n0 + wn + nt*16 + lr;
        if (gn >= p.N) continue;
        float val = acc[mt][nt][r];
        if (EPI == 0) {
          p.C[(long)z*p.cz + (long)gm*p.ldc + gn] = val;
        } else {   // qk scatter
          int which = (gn >= CD) ? 1 : 0;
          int rc = gn - which*CD;   // FIXED: was gn & (CD-1), wrong for non-pow2 CD
          int hd = rc >> 6, dd = rc & 63;
          int cb = gm / NTOK, tok = gm - cb*NTOK;
          float* tgt = which ? p.k : p.q;
          tgt[(((long)cb*NH + hd)*NTOK + tok)*DH + dd] = which ? val : val*0.125f;
        }
      }
    }
  }
}

// ---------------- softmax: one wave per row of 197, in-place fp32 ----------------
__global__ __launch_bounds__(256) void softmax_kernel(float* __restrict__ attn)
{
  long row = (long)blockIdx.x*4 + (threadIdx.x>>6);
  int ln = threadIdx.x & 63;
  float* rp = attn + row*NTOK;
  float v[4]; float mx = -3.4e38f;
#pragma unroll
  for (int i=0;i<4;i++){
    int c = ln + i*64;
    v[i] = (c < NTOK) ? rp[c] : -3.4e38f;
    mx = fmaxf(mx, v[i]);
  }
#pragma unroll
  for (int off=32; off; off>>=1) mx = fmaxf(mx, __shfl_xor(mx, off));
  float sum = 0.f;
#pragma unroll
  for (int i=0;i<4;i++){
    int c = ln + i*64;
    v[i] = (c < NTOK) ? expf(v[i]-mx) : 0.f;
    sum += v[i];
  }
#pragma unroll
  for (int off=32; off; off>>=1) sum += __shfl_xor(sum, off);
#pragma unroll
  for (int i=0;i<4;i++){
    int c = ln + i*64;
    if (c < NTOK) rp[c] = v[i] / sum;
  }
}

// ---------------- token selection ----------------
__global__ __launch_bounds__(256) void select_kernel(const float* __restrict__ attn,
                                                     int* __restrict__ idx_kept,
                                                     int* __restrict__ idx_elim, int b0)
{
  int cb = blockIdx.x, tid = threadIdx.x;
  int b = b0 + cb;
  __shared__ float diag[NTOK-1];
  __shared__ int kept[NTOK];
  if (tid < NTOK-1) {
    int t = tid + 1;
    float s = 0.f;
#pragma unroll
    for (int h=0; h<NH; h++)
      s += attn[(((long)cb*NH + h)*NTOK + t)*NTOK + t];
    diag[tid] = s / 12.0f;
  }
  if (tid < KTOK) idx_kept[b*KTOK + tid] = 0;
  if (tid < RTOK) idx_elim[b*RTOK + tid] = 1;
  __syncthreads();
  if (tid < NTOK-1) {
    float dv = diag[tid];
    int r = 0;
    for (int m=0; m<NTOK-1; m++){
      float dm = diag[m];
      r += ((dm > dv) || (dm == dv && m < tid)) ? 1 : 0;
    }
    kept[tid+1] = (r < (NTOK-1-RTOK)) ? 1 : 0;
  }
  __syncthreads();
  if (tid < NTOK-1) {
    int t = tid + 1;
    if (kept[t]) {
      int pos = 1;
      for (int s2=1; s2<t; s2++) pos += kept[s2];
      if (pos >= 1 && pos < KTOK) idx_kept[b*KTOK + pos] = t;
    } else {
      int pos = 0;
      for (int s2=1; s2<t; s2++) pos += 1 - kept[s2];
      if (pos >= 0 && pos < RTOK) idx_elim[b*RTOK + pos] = t;
    }
  }
  if (tid == 0) idx_kept[b*KTOK] = 0;
}

// ---------------- fused threshold + propagation ----------------
__global__ __launch_bounds__(256) void prop_kernel(const float* __restrict__ attn,
                                                   const float* __restrict__ x1c,
                                                   const int* __restrict__ idx_kept,
                                                   const int* __restrict__ idx_elim,
                                                   float* __restrict__ x2, int b0)
{
  int z = blockIdx.x;
  int cb = z / NH, h = z - cb*NH;
  int b = b0 + cb;
  int tid = threadIdx.x;
  __shared__ float w[KTOK*RTOK];
  __shared__ unsigned short xe[RTOK*DH];
  __shared__ int kidx[KTOK], eidx[RTOK];
  __shared__ int cw[4];
  __shared__ int ctot;
  if (tid < KTOK) kidx[tid] = clamp196(idx_kept[b*KTOK + tid]);
  if (tid < RTOK) eidx[tid] = clamp196(idx_elim[b*RTOK + tid]);
  __syncthreads();
  const float* ab = attn + (long)z*NTOK*NTOK;
  for (int i=tid; i<KTOK*RTOK; i+=256){
    int k = i / RTOK, e = i - k*RTOK;
    w[i] = ab[kidx[k]*NTOK + eidx[e]];
  }
  for (int i=tid; i<RTOK*DH; i+=256){
    int e = i >> 6, d = i & 63;
    xe[i] = f2b(x1c[((long)cb*NTOK + eidx[e])*CD + h*DH + d]);
  }
  __syncthreads();
  unsigned lo = 0u, hi = 0x3f800001u;
  while (hi - lo > 1u) {
    unsigned mid = (lo + hi) >> 1;
    float t = __uint_as_float(mid);
    int c = 0;
    for (int i=tid; i<KTOK*RTOK; i+=256) c += (w[i] >= t) ? 1 : 0;
#pragma unroll
    for (int off=32; off; off>>=1) c += __shfl_down(c, off);
    if ((tid & 63) == 0) cw[tid>>6] = c;
    __syncthreads();
    if (tid == 0) ctot = cw[0]+cw[1]+cw[2]+cw[3];
    __syncthreads();
    int tot = ctot;
    __syncthreads();
    if (tot >= THRN) lo = mid; else hi = mid;
  }
  float tv = __uint_as_float(lo);
  for (int i=tid; i<KTOK*RTOK; i+=256) if (w[i] < tv) w[i] = 0.f;
  __syncthreads();
  int d = tid & 63;
  for (int k = tid>>6; k < KTOK; k += 4) {
    const float* wr = &w[k*RTOK];
    float acc = 0.f;
#pragma unroll 7
    for (int e=0; e<RTOK; e++)
      acc = fmaf(wr[e], us2f(xe[(e<<6) + d]), acc);
    float xk = x1c[((long)cb*NTOK + kidx[k])*CD + h*DH + d];
    x2[((long)b*KTOK + k)*CD + h*DH + d] = xk + 0.1f*acc;
  }
}

extern "C" void kernel_launch(void* const* d_in, const int* in_sizes, int n_in,
                              void* d_out, int out_size, void* d_ws, size_t ws_size,
                              hipStream_t stream)
{
  const float* x     = (const float*)d_in[0];
  const float* n1g   = (const float*)d_in[1];
  const float* n1b   = (const float*)d_in[2];
  const float* qkvw  = (const float*)d_in[3];
  const float* projw = (const float*)d_in[4];
  const float* projb = (const float*)d_in[5];
  const float* n2g   = (const float*)d_in[6];
  const float* n2b   = (const float*)d_in[7];
  const float* fc1w  = (const float*)d_in[8];
  const float* fc1b  = (const float*)d_in[9];
  const float* fc2w  = (const float*)d_in[10];
  const float* fc2b  = (const float*)d_in[11];
  float* out = (float*)d_out;

  const long XROW = (long)NTOK*CD;          // 151296
  const long AH   = (long)NTOK*NTOK;        // 38809
  const long AB   = (long)NH*AH;            // 465708
  const long QH   = (long)NH*NTOK*DH;       // 151296
  const long SMALL = 6336L + 6272L;         // 12608 floats
  const long WFIX  = 1769472L;              // qkwh+qkwl+qkvwvT+projwT (floats)
  const long PB = AB + 3*XROW + XROW/2;     // 995,244 floats per batch
  const long MLPFIX = 2359296L;             // fc1wT+fc2wT (floats), in chunk area
  const long MINREQ = SMALL + WFIX + (MLPFIX + 64*1920L > PB ? MLPFIX + 64*1920L : PB);

  long wsf = (long)(ws_size / 4);
  if (wsf < MINREQ) {
    float val = (float)(ws_size >> 20) * 1000.0f + 1.0f;
    fill_kernel<<<dim3((out_size+255)/256), 256, 0, stream>>>(out, out_size, val);
    return;
  }

  long avail = wsf - SMALL - WFIX;
  int G = (int)(avail / PB);
  if (G > NBATCH) G = NBATCH;
  if (G < 1) G = 1;
  long rcl = ((avail - MLPFIX) / 1920L) / 64L * 64L;
  int RC = (int)(rcl > 6336L ? 6336L : rcl);
  if (RC < 64) RC = 64;

  float* ws = (float*)d_ws;
  int*   idx_kept = (int*)ws;
  int*   idx_elim = idx_kept + 6336;
  unsigned short* qkwh   = (unsigned short*)(ws + SMALL);   // [1536][768]
  unsigned short* qkwl   = qkwh + 1179648;                  // [1536][768]
  unsigned short* qkvwvT = qkwl + 1179648;                  // [768][768]
  unsigned short* projwT = qkvwvT + 589824;                 // [768][768]
  float* base  = ws + SMALL + WFIX;
  float* attnc = base;                                      // G*AB
  float* qf    = base + (long)G*AB;                         // G*XROW (x1c alias)
  float* x1c   = qf;
  float* kf    = qf + (long)G*XROW;                         // G*XROW (aoutb alias)
  unsigned short* aoutb = (unsigned short*)kf;
  unsigned short* vc = (unsigned short*)(kf + (long)G*XROW);   // G*XROW bf16
  float* h1f   = kf + (long)G*XROW + (long)G*XROW/2;        // G*XROW
  // MLP phase (chunk area reuse):
  unsigned short* fc1wT = (unsigned short*)base;            // [3072][768]
  unsigned short* fc2wT = fc1wT + 2359296;                  // [768][3072]
  unsigned short* h2b   = (unsigned short*)(base + MLPFIX); // RC*768
  unsigned short* gb    = h2b + (long)RC*CD;                // RC*3072

  // Phase 0: weight prep for attention
  tcast3_k<<<dim3(48,24), 256, 0, stream>>>(qkvw, CD, 3*CD, 0, qkwh, qkwl);
  tcast_k <<<dim3(24,24), 256, 0, stream>>>(qkvw, CD, 3*CD, 2*CD, qkvwvT);
  tcast_k <<<dim3(24,24), 256, 0, stream>>>(projw, CD, CD, 0, projwT);

  for (int b0 = 0; b0 < NBATCH; b0 += G) {
    int GL = (NBATCH - b0 < G) ? (NBATCH - b0) : G;
    int MROW = GL*NTOK;
    // LN1 -> h1f fp32
    ln_kernel<<<dim3(MROW), 256, 0, stream>>>(x + (long)b0*XROW, n1g, n1b, h1f, nullptr);
    // qk bf16x3 MFMA: h1f @ qkw^T -> qf(scaled), kf (both [bh][tok][dh] fp32)
    {
      Mm3P p{}; p.A=h1f; p.Bh=qkwh; p.Bl=qkwl; p.q=qf; p.k=kf;
      p.M=MROW; p.N=2*CD; p.K=CD; p.ldc=0; p.az=0; p.cz=0;
      mgemm3_k<1,1><<<dim3(12,(MROW+127)/128,1), 256, 0, stream>>>(p);
    }
    // v MFMA (single bf16): h1f @ qkvwvT^T -> vc bf16 scatter
    {
      MmP p{}; p.Af=h1f; p.B=qkvwvT; p.vout=vc;
      p.M=MROW; p.N=CD; p.K=CD; p.ldc=CD;
      mgemm_k<1,1><<<dim3(6,(MROW+127)/128,1), 256, 0, stream>>>(p);
    }
    // S = q @ k^T bf16x3 MFMA per (b,h) -> attnc fp32
    {
      Mm3P p{}; p.A=qf; p.Bf=kf; p.C=attnc;
      p.M=NTOK; p.N=NTOK; p.K=DH; p.ldc=NTOK;
      p.az=(long)NTOK*DH; p.bz=(long)NTOK*DH; p.cz=AH;
      mgemm3_k<0,0><<<dim3(2,2,GL*NH), 256, 0, stream>>>(p);
    }
    softmax_kernel<<<dim3(GL*591), 256, 0, stream>>>(attnc);
    select_kernel<<<dim3(GL), 256, 0, stream>>>(attnc, idx_kept, idx_elim, b0);
    // attn @ v (fp32 A, bf16 B) -> aoutb bf16
    {
      GemmP p{}; p.A=attnc; p.B=vc; p.C=aoutb;
      p.M=NTOK; p.N=DH; p.K=NTOK; p.ldb=DH; p.ldc=CD; p.zdiv=NH;
      p.as0=AB; p.as1=AH; p.bs0=QH; p.bs1=(long)NTOK*DH; p.cs0=XROW; p.cs1=DH;
      gemm_k<2,1><<<dim3(1,4,GL*NH), 256, 0, stream>>>(p);
    }
    // proj MFMA: x1c = x + aoutb @ projwT^T + proj_b (fp32)
    {
      MmP p{}; p.A=aoutb; p.B=projwT; p.C=x1c;
      p.M=MROW; p.N=CD; p.K=CD; p.ldc=CD;
      p.bias=projb; p.resid=x + (long)b0*XROW;
      mgemm_k<0,2><<<dim3(6,(MROW+127)/128,1), 256, 0, stream>>>(p);
    }
    // fused threshold + propagation -> x2 (f32) in d_out
    prop_kernel<<<dim3(GL*NH), 256, 0, stream>>>(attnc, x1c, idx_kept, idx_elim, out, b0);
  }

  // ---- MLP weight prep (chunk area now free) ----
  tcast_k<<<dim3(96,24), 256, 0, stream>>>(fc1w, CD, 4*CD, 0, fc1wT);
  tcast_k<<<dim3(24,96), 256, 0, stream>>>(fc2w, 4*CD, CD, 0, fc2wT);

  // ---- MLP, row-chunked; x2 lives in d_out (f32), fc2 overwrites in place ----
  for (int r0 = 0; r0 < NBATCH*KTOK; r0 += RC) {
    int RCL = (NBATCH*KTOK - r0 < RC) ? (NBATCH*KTOK - r0) : RC;
    ln_kernel<<<dim3(RCL), 256, 0, stream>>>(out + (long)r0*CD, n2g, n2b, nullptr, h2b);
    {
      MmP p{}; p.A=h2b; p.B=fc1wT; p.C=gb;
      p.M=RCL; p.N=4*CD; p.K=CD; p.ldc=4*CD; p.bias=fc1b;
      mgemm_k<0,3><<<dim3(24,(RCL+127)/128,1), 256, 0, stream>>>(p);
    }
    {
      MmP p{}; p.A=gb; p.B=fc2wT; p.C=out + (long)r0*CD;
      p.M=RCL; p.N=CD; p.K=4*CD; p.ldc=CD;
      p.bias=fc2b; p.resid=out + (long)r0*CD;
      mgemm_k<0,2><<<dim3(6,(RCL+127)/128,1), 256, 0, stream>>>(p);
    }
  }
}